// Round 7
// baseline (1591.064 us; speedup 1.0000x reference)
//
#include <hip/hip_runtime.h>

// Problem constants
#define B_    4
#define N_    16384
#define D_    64
#define Q_    128
#define E_    131072
#define M_    4
#define BN    65536        // B*N
#define TOTE  524288       // B*E
#define ITERS 25
#define PAD_CAP (TOTE + 3 * BN + 64)   // padded-CSR capacity (edges)

// Output layout (f32, concatenated flat):
//   nf:         (4,5,64)      = 1280   @ 0
//   masks_ext:  (4,5,128,128) = 327680 @ 1280
//   node_scores:(4,5)         = 20     @ 328960
#define OFF_MASKS 1280
#define OFF_SCORES 328960

__constant__ int c_agidx[4] = {0, 5461, 10922, 16383};

// pack two f32 -> (bf16,bf16) in one uint, RTNE
__device__ __forceinline__ unsigned pack_bf16x2(float x, float y) {
    unsigned ux = __float_as_uint(x);
    unsigned uy = __float_as_uint(y);
    ux = (ux + 0x7fffu + ((ux >> 16) & 1u)) >> 16;          // low 16 = bf16(x)
    uy = (uy + 0x7fffu + ((uy >> 16) & 1u)) & 0xffff0000u;  // high 16 = bf16(y)
    return ux | uy;
}

// ---------- CSR build ----------
__global__ void k_count(const int* __restrict__ edges, const float* __restrict__ wts,
                        int* __restrict__ deg) {
    int idx = blockIdx.x * blockDim.x + threadIdx.x;
    if (idx >= TOTE) return;
    int b = idx >> 17;           // / E_
    int e = idx & (E_ - 1);
    float w = wts[idx];          // (B,E) flat == idx
    if (w > 0.5f) {
        int row = edges[(b * 2) * E_ + e];
        atomicAdd(&deg[row], 1);
    }
}

// ---- parallel scan over padded degrees ----
__global__ __launch_bounds__(256) void k_scan1(const int* __restrict__ deg,
                                               int* __restrict__ blockSums) {
    int i = blockIdx.x * 256 + threadIdx.x;
    int v = (deg[i] + 3) & ~3;
    #pragma unroll
    for (int off = 1; off < 64; off <<= 1) v += __shfl_xor(v, off, 64);
    __shared__ int ws[4];
    int lane = threadIdx.x & 63, w = threadIdx.x >> 6;
    if (lane == 0) ws[w] = v;
    __syncthreads();
    if (threadIdx.x == 0)
        blockSums[blockIdx.x] = ws[0] + ws[1] + ws[2] + ws[3];
}

// each block redundantly scans the 256 block sums, then rescans its 256 rows
__global__ __launch_bounds__(256) void k_scan3(const int* __restrict__ deg,
                                               const int* __restrict__ blockSums,
                                               int* __restrict__ row_start,
                                               int* __restrict__ cursor) {
    int t = threadIdx.x;
    int lane = t & 63, w = t >> 6;
    __shared__ int offs[256];
    __shared__ int wtotA[4];
    __shared__ int wtotB[4];

    int bs = blockSums[t];
    int binc = bs;
    #pragma unroll
    for (int off = 1; off < 64; off <<= 1) {
        int u = __shfl_up(binc, off, 64);
        if (lane >= off) binc += u;
    }
    if (lane == 63) wtotA[w] = binc;
    __syncthreads();
    int badd = 0;
    for (int j = 0; j < w; ++j) badd += wtotA[j];
    offs[t] = binc + badd - bs;        // exclusive prefix of blockSums
    if (blockIdx.x == 0 && t == 255) row_start[BN] = binc + badd;
    __syncthreads();
    int blockOff = offs[blockIdx.x];

    int i = blockIdx.x * 256 + t;
    int v = (deg[i] + 3) & ~3;
    int incl = v;
    #pragma unroll
    for (int off = 1; off < 64; off <<= 1) {
        int u = __shfl_up(incl, off, 64);
        if (lane >= off) incl += u;
    }
    if (lane == 63) wtotB[w] = incl;
    __syncthreads();
    int wadd = 0;
    for (int j = 0; j < w; ++j) wadd += wtotB[j];
    int rs = blockOff + wadd + incl - v;
    row_start[i] = rs;
    cursor[i] = rs;
}

__global__ void k_scatter(const int* __restrict__ edges, const float* __restrict__ wts,
                          int* __restrict__ cursor, int2* __restrict__ cw) {
    int idx = blockIdx.x * blockDim.x + threadIdx.x;
    if (idx >= TOTE) return;
    int b = idx >> 17;
    int e = idx & (E_ - 1);
    float w = wts[idx];
    if (w > 0.5f) {
        int row = edges[(b * 2) * E_ + e];
        int col = edges[(b * 2) * E_ + E_ + e];
        int pos = atomicAdd(&cursor[row], 1);
        cw[pos] = make_int2(col, __float_as_int(w));
    }
}

// Deterministic order within each row's REAL segment: sort by (col, w-bits).
// Also writes the (0,0) padding entries up to the 4-aligned row end.
__global__ void k_sort(const int* __restrict__ row_start, const int* __restrict__ deg,
                       int2* __restrict__ cw) {
    int n = blockIdx.x * blockDim.x + threadIdx.x;
    if (n >= BN) return;
    int s = row_start[n], epos = s + deg[n], pend = row_start[n + 1];
    for (int i = s + 1; i < epos; ++i) {
        int2 v = cw[i];
        unsigned long long key =
            ((unsigned long long)(unsigned)v.x << 32) | (unsigned)v.y;
        int j = i - 1;
        while (j >= s) {
            int2 u = cw[j];
            unsigned long long kj =
                ((unsigned long long)(unsigned)u.x << 32) | (unsigned)u.y;
            if (kj <= key) break;
            cw[j + 1] = u;
            --j;
        }
        cw[j + 1] = v;
    }
    for (int i = epos; i < pend; ++i) cw[i] = make_int2(0, 0);
}

// ---- degree-bucket counting sort: group equal-chunk-count nodes per wave ----
__global__ void k_hist(const int* __restrict__ deg, int* __restrict__ hist) {
    int n = blockIdx.x * 256 + threadIdx.x;
    int c = (deg[n] + 3) >> 2;
    if (c > 255) c = 255;
    atomicAdd(&hist[c], 1);
}

__global__ __launch_bounds__(256) void k_bucketscan(const int* __restrict__ hist,
                                                    int* __restrict__ bucketCur) {
    int t = threadIdx.x;
    int lane = t & 63, w = t >> 6;
    int v = hist[t];
    int incl = v;
    #pragma unroll
    for (int off = 1; off < 64; off <<= 1) {
        int u = __shfl_up(incl, off, 64);
        if (lane >= off) incl += u;
    }
    __shared__ int wtot[4];
    if (lane == 63) wtot[w] = incl;
    __syncthreads();
    int wadd = 0;
    for (int j = 0; j < w; ++j) wadd += wtot[j];
    bucketCur[t] = incl + wadd - v;    // exclusive
}

__global__ void k_permscatter(const int* __restrict__ deg, int* __restrict__ bucketCur,
                              int* __restrict__ perm) {
    int n = blockIdx.x * 256 + threadIdx.x;
    int c = (deg[n] + 3) >> 2;
    if (c > 255) c = 255;
    int pos = atomicAdd(&bucketCur[c], 1);
    perm[pos] = n;
}

// ---------- propagation: FOUR degree-matched nodes per wave ----------
// perm groups nodes of equal chunk count -> 16 gathers in flight with
// near-zero padded replay. Per-node arithmetic bit-exact regardless of
// grouping (padding carries w=0.0; fmaf(0,v,acc)==acc for finite v).
template <bool F32IN>
__global__ __launch_bounds__(256) void k_prop(const void* __restrict__ hin,
                                              unsigned* __restrict__ hout,
                                              const int* __restrict__ row_start,
                                              const int2* __restrict__ cw,
                                              const int* __restrict__ perm) {
    int lane = threadIdx.x & 63;
    int gid = (blockIdx.x << 2) + (threadIdx.x >> 6);   // 0..16383
    int base = __builtin_amdgcn_readfirstlane(gid << 2);
    const int4 p4 = *(const int4*)(perm + base);        // uniform -> s_load
    int u0 = __builtin_amdgcn_readfirstlane(p4.x);
    int u1 = __builtin_amdgcn_readfirstlane(p4.y);
    int u2 = __builtin_amdgcn_readfirstlane(p4.z);
    int u3 = __builtin_amdgcn_readfirstlane(p4.w);
    int s0 = row_start[u0], e0 = row_start[u0 + 1];
    int s1 = row_start[u1], e1 = row_start[u1 + 1];
    int s2 = row_start[u2], e2 = row_start[u2 + 1];
    int s3 = row_start[u3], e3 = row_start[u3 + 1];
    int c0 = (e0 - s0) >> 2, c1 = (e1 - s1) >> 2;
    int c2 = (e2 - s2) >> 2, c3 = (e3 - s3) >> 2;
    int m01 = c0 > c1 ? c0 : c1, m23 = c2 > c3 ? c2 : c3;
    int nmax = m01 > m23 ? m01 : m23;
    int b0 = c0 ? s0 : 0, b1 = c1 ? s1 : 0, b2 = c2 ? s2 : 0, b3 = c3 ? s3 : 0;
    int l0 = (c0 ? c0 : 1) - 1, l1 = (c1 ? c1 : 1) - 1;
    int l2 = (c2 ? c2 : 1) - 1, l3 = (c3 ? c3 : 1) - 1;

    auto gather = [&](int col) -> float2 {
        if constexpr (F32IN) {
            return ((const float2*)hin)[((size_t)col << 6) + lane];
        } else {
            unsigned p = ((const unsigned*)hin)[((size_t)col << 6) + lane];
            float2 r;
            r.x = __uint_as_float(p << 16);
            r.y = __uint_as_float(p & 0xffff0000u);
            return r;
        }
    };

    float ax0 = 0.f, ay0 = 0.f, ax1 = 0.f, ay1 = 0.f;
    float ax2 = 0.f, ay2 = 0.f, ax3 = 0.f, ay3 = 0.f;
    for (int j = 0; j < nmax; ++j) {
        int j0 = j < l0 ? j : l0, j1 = j < l1 ? j : l1;
        int j2 = j < l2 ? j : l2, j3 = j < l3 ? j : l3;
        const int4* q0 = (const int4*)(cw + b0 + (j0 << 2));
        const int4* q1 = (const int4*)(cw + b1 + (j1 << 2));
        const int4* q2 = (const int4*)(cw + b2 + (j2 << 2));
        const int4* q3 = (const int4*)(cw + b3 + (j3 << 2));
        int4 a0 = q0[0], a1 = q0[1];
        int4 a2 = q1[0], a3 = q1[1];
        int4 a4 = q2[0], a5 = q2[1];
        int4 a6 = q3[0], a7 = q3[1];
        // 16 gathers in flight
        float2 v00 = gather(a0.x), v01 = gather(a0.z);
        float2 v02 = gather(a1.x), v03 = gather(a1.z);
        float2 v10 = gather(a2.x), v11 = gather(a2.z);
        float2 v12 = gather(a3.x), v13 = gather(a3.z);
        float2 v20 = gather(a4.x), v21 = gather(a4.z);
        float2 v22 = gather(a5.x), v23 = gather(a5.z);
        float2 v30 = gather(a6.x), v31 = gather(a6.z);
        float2 v32 = gather(a7.x), v33 = gather(a7.z);
        bool k0 = j < c0, k1 = j < c1, k2 = j < c2, k3 = j < c3;
        float w00 = k0 ? __int_as_float(a0.y) : 0.f;
        float w01 = k0 ? __int_as_float(a0.w) : 0.f;
        float w02 = k0 ? __int_as_float(a1.y) : 0.f;
        float w03 = k0 ? __int_as_float(a1.w) : 0.f;
        float w10 = k1 ? __int_as_float(a2.y) : 0.f;
        float w11 = k1 ? __int_as_float(a2.w) : 0.f;
        float w12 = k1 ? __int_as_float(a3.y) : 0.f;
        float w13 = k1 ? __int_as_float(a3.w) : 0.f;
        float w20 = k2 ? __int_as_float(a4.y) : 0.f;
        float w21 = k2 ? __int_as_float(a4.w) : 0.f;
        float w22 = k2 ? __int_as_float(a5.y) : 0.f;
        float w23 = k2 ? __int_as_float(a5.w) : 0.f;
        float w30 = k3 ? __int_as_float(a6.y) : 0.f;
        float w31 = k3 ? __int_as_float(a6.w) : 0.f;
        float w32 = k3 ? __int_as_float(a7.y) : 0.f;
        float w33 = k3 ? __int_as_float(a7.w) : 0.f;
        ax0 = fmaf(w00, v00.x, ax0); ay0 = fmaf(w00, v00.y, ay0);
        ax0 = fmaf(w01, v01.x, ax0); ay0 = fmaf(w01, v01.y, ay0);
        ax0 = fmaf(w02, v02.x, ax0); ay0 = fmaf(w02, v02.y, ay0);
        ax0 = fmaf(w03, v03.x, ax0); ay0 = fmaf(w03, v03.y, ay0);
        ax1 = fmaf(w10, v10.x, ax1); ay1 = fmaf(w10, v10.y, ay1);
        ax1 = fmaf(w11, v11.x, ax1); ay1 = fmaf(w11, v11.y, ay1);
        ax1 = fmaf(w12, v12.x, ax1); ay1 = fmaf(w12, v12.y, ay1);
        ax1 = fmaf(w13, v13.x, ax1); ay1 = fmaf(w13, v13.y, ay1);
        ax2 = fmaf(w20, v20.x, ax2); ay2 = fmaf(w20, v20.y, ay2);
        ax2 = fmaf(w21, v21.x, ax2); ay2 = fmaf(w21, v21.y, ay2);
        ax2 = fmaf(w22, v22.x, ax2); ay2 = fmaf(w22, v22.y, ay2);
        ax2 = fmaf(w23, v23.x, ax2); ay2 = fmaf(w23, v23.y, ay2);
        ax3 = fmaf(w30, v30.x, ax3); ay3 = fmaf(w30, v30.y, ay3);
        ax3 = fmaf(w31, v31.x, ax3); ay3 = fmaf(w31, v31.y, ay3);
        ax3 = fmaf(w32, v32.x, ax3); ay3 = fmaf(w32, v32.y, ay3);
        ax3 = fmaf(w33, v33.x, ax3); ay3 = fmaf(w33, v33.y, ay3);
    }
    float ss0 = ax0 * ax0 + ay0 * ay0;
    float ss1 = ax1 * ax1 + ay1 * ay1;
    float ss2 = ax2 * ax2 + ay2 * ay2;
    float ss3 = ax3 * ax3 + ay3 * ay3;
    #pragma unroll
    for (int off = 32; off; off >>= 1) {
        ss0 += __shfl_xor(ss0, off, 64);
        ss1 += __shfl_xor(ss1, off, 64);
        ss2 += __shfl_xor(ss2, off, 64);
        ss3 += __shfl_xor(ss3, off, 64);
    }
    float i0 = 1.0f / (sqrtf(ss0) + 1e-8f);
    float i1 = 1.0f / (sqrtf(ss1) + 1e-8f);
    float i2 = 1.0f / (sqrtf(ss2) + 1e-8f);
    float i3 = 1.0f / (sqrtf(ss3) + 1e-8f);
    hout[((size_t)u0 << 6) + lane] = pack_bf16x2(ax0 * i0, ay0 * i0);
    hout[((size_t)u1 << 6) + lane] = pack_bf16x2(ax1 * i1, ay1 * i1);
    hout[((size_t)u2 << 6) + lane] = pack_bf16x2(ax2 * i2, ay2 * i2);
    hout[((size_t)u3 << 6) + lane] = pack_bf16x2(ax3 * i3, ay3 * i3);
}

// ---------- competition: wave per row (bf16 h) ----------
__global__ __launch_bounds__(256) void k_masks(const unsigned* __restrict__ h,
                                               float* __restrict__ masks) {
    int wave = threadIdx.x >> 6;
    int lane = threadIdx.x & 63;
    int n = blockIdx.x * 4 + wave;      // global row 0..65535
    int b = n >> 14;
    int nl = n & (N_ - 1);
    unsigned vp = h[((size_t)n << 6) + lane];
    float vx = __uint_as_float(vp << 16);
    float vy = __uint_as_float(vp & 0xffff0000u);
    float dot[4];
    #pragma unroll
    for (int m = 0; m < 4; ++m) {
        int an = b * N_ + c_agidx[m];
        unsigned ap = h[((size_t)an << 6) + lane];
        float axx = __uint_as_float(ap << 16);
        float ayy = __uint_as_float(ap & 0xffff0000u);
        float d = vx * axx + vy * ayy;
        #pragma unroll
        for (int off = 32; off; off >>= 1) d += __shfl_xor(d, off, 64);
        dot[m] = d;
    }
    const float scl = 0.0883883476483184405501055452631f; // 1/sqrt(128)
    float l0 = dot[0] * scl, l1 = dot[1] * scl, l2 = dot[2] * scl, l3 = dot[3] * scl;
    float mx = fmaxf(fmaxf(fmaxf(l0, l1), fmaxf(l2, l3)), 0.f);
    float e0 = expf(l0 - mx), e1 = expf(l1 - mx), e2 = expf(l2 - mx),
          e3 = expf(l3 - mx), e4 = expf(0.f - mx);
    float den = e0 + e1 + e2 + e3 + e4;
    if (lane < 5) {
        float p = (lane == 0) ? e0 : (lane == 1) ? e1 : (lane == 2) ? e2
                  : (lane == 3) ? e3 : e4;
        masks[((size_t)b * 5 + lane) * N_ + nl] = p / den;
    }
}

// ---------- nf partials + chunk maxes: ONE feat pass for all 5 masks ----------
// grid: 4 b x 64 chunks; each block covers 256 rows, all 5 m-channels
__global__ __launch_bounds__(256) void k_nfpart(const float* __restrict__ feat,
                                                const float* __restrict__ masks,
                                                float* __restrict__ part,
                                                float* __restrict__ maxpart) {
    int b = blockIdx.x >> 6;
    int chunk = blockIdx.x & 63;
    int d = threadIdx.x & 63;
    int g = threadIdx.x >> 6;   // wave id 0..3
    int n0 = chunk * 256 + g * 64;
    const float* fb = feat + (size_t)b * N_ * D_;
    float acc[5] = {0.f, 0.f, 0.f, 0.f, 0.f};
    float mxv[5] = {-1e30f, -1e30f, -1e30f, -1e30f, -1e30f};
    for (int i = 0; i < 64; ++i) {
        int n = n0 + i;
        float fv = fb[(size_t)n * D_ + d];
        #pragma unroll
        for (int m = 0; m < 5; ++m) {
            float mv = masks[((size_t)b * 5 + m) * N_ + n];  // uniform -> s_load
            acc[m] = fmaf(fv, mv, acc[m]);
            mxv[m] = fmaxf(mxv[m], mv);
        }
    }
    __shared__ float lds[4][5][64];
    __shared__ float lmx[4][5];
    #pragma unroll
    for (int m = 0; m < 5; ++m) lds[g][m][d] = acc[m];
    if (d == 0) {
        #pragma unroll
        for (int m = 0; m < 5; ++m) lmx[g][m] = mxv[m];
    }
    __syncthreads();
    if (g == 0) {
        #pragma unroll
        for (int m = 0; m < 5; ++m) {
            float s = lds[0][m][d] + lds[1][m][d] + lds[2][m][d] + lds[3][m][d];
            part[(((size_t)b * 64 + chunk) * 5 + m) * 64 + d] = s;
            if (d == 0)
                maxpart[((size_t)b * 64 + chunk) * 5 + m] =
                    fmaxf(fmaxf(lmx[0][m], lmx[1][m]), fmaxf(lmx[2][m], lmx[3][m]));
        }
    }
}

// ---------- final: sum chunks, normalize over m-axis, scores ----------
__global__ void k_nffinal(const float* __restrict__ part, const float* __restrict__ maxpart,
                          float* __restrict__ out) {
    int b = blockIdx.x;     // 4 blocks
    int d = threadIdx.x;    // 64 threads
    float v[5];
    float ss = 0.f;
    for (int m = 0; m < 5; ++m) {
        float s = 0.f;
        for (int c = 0; c < 64; ++c)
            s += part[(((size_t)b * 64 + c) * 5 + m) * 64 + d];
        v[m] = s;
        ss += s * s;
    }
    float nrm = fmaxf(sqrtf(ss), 1e-12f);
    for (int m = 0; m < 5; ++m) out[((size_t)b * 5 + m) * 64 + d] = v[m] / nrm;
    if (d < 5) {
        float mx = -1e30f;
        for (int c = 0; c < 64; ++c)
            mx = fmaxf(mx, maxpart[((size_t)b * 64 + c) * 5 + d]);
        out[OFF_SCORES + b * 5 + d] = mx;
    }
}

extern "C" void kernel_launch(void* const* d_in, const int* in_sizes, int n_in,
                              void* d_out, int out_size, void* d_ws, size_t ws_size,
                              hipStream_t stream) {
    const float* feat  = (const float*)d_in[0];   // (4,16384,64)
    const int*   edges = (const int*)d_in[1];     // (4,2,131072)
    const float* wts   = (const float*)d_in[2];   // (4,131072)
    const float* init  = (const float*)d_in[3];   // (4,16384,128)
    float* out = (float*)d_out;

    // workspace layout (bf16 h: 65536 rows x 64 uints = 16 MB each)
    unsigned* hA = (unsigned*)d_ws;
    unsigned* hB = hA + (size_t)BN * 64;
    int* row_start  = (int*)(hB + (size_t)BN * 64);   // 65537 (+pad)
    int* cursor     = row_start + 65544;              // 65536
    int* deg        = cursor + BN;                    // 65536
    int* hist       = deg + BN;                       // 256 (memset with deg)
    int* blockSums  = hist + 256;                     // 256
    int* bucketCur  = blockSums + 256;                // 256
    int* perm       = bucketCur + 256;                // 65536
    int2* cw        = (int2*)(perm + BN);             // PAD_CAP int2 (~5.8 MB)
    float* part     = (float*)(cw + PAD_CAP);         // 4*64*5*64 = 81920
    float* maxpart  = part + 81920;                   // 1280

    // CSR build (padded rows, interleaved (col,w) pairs; padding written by k_sort)
    hipMemsetAsync(deg, 0, (BN + 256) * sizeof(int), stream);   // deg + hist
    k_count<<<TOTE / 256, 256, 0, stream>>>(edges, wts, deg);
    k_scan1<<<256, 256, 0, stream>>>(deg, blockSums);
    k_scan3<<<256, 256, 0, stream>>>(deg, blockSums, row_start, cursor);
    k_scatter<<<TOTE / 256, 256, 0, stream>>>(edges, wts, cursor, cw);
    k_sort<<<BN / 256, 256, 0, stream>>>(row_start, deg, cw);
    // degree-bucket grouping permutation
    k_hist<<<BN / 256, 256, 0, stream>>>(deg, hist);
    k_bucketscan<<<1, 256, 0, stream>>>(hist, bucketCur);
    k_permscatter<<<BN / 256, 256, 0, stream>>>(deg, bucketCur, perm);

    // 25 propagation iterations; iter 0 reads f32 init directly
    k_prop<true><<<BN / 16, 256, 0, stream>>>(init, hA, row_start, cw, perm);
    const unsigned* src = hA;
    for (int it = 1; it < ITERS; ++it) {
        unsigned* dst = (it & 1) ? hB : hA;
        k_prop<false><<<BN / 16, 256, 0, stream>>>(src, dst, row_start, cw, perm);
        src = dst;
    }

    // competition + outputs
    k_masks<<<BN / 4, 256, 0, stream>>>(src, out + OFF_MASKS);
    k_nfpart<<<4 * 64, 256, 0, stream>>>(feat, out + OFF_MASKS, part, maxpart);
    k_nffinal<<<4, 64, 0, stream>>>(part, maxpart, out);
}

// Round 8
// 563.605 us; speedup vs baseline: 2.8230x; 2.8230x over previous
//
#include <hip/hip_runtime.h>

// Problem constants
#define B_    4
#define N_    16384
#define D_    64
#define Q_    128
#define E_    131072
#define M_    4
#define BN    65536        // B*N
#define TOTE  524288       // B*E
#define ITERS 25
#define PAD_CAP (TOTE + 3 * BN + 64)   // padded-CSR capacity (edges)

// Output layout (f32, concatenated flat):
//   nf:         (4,5,64)      = 1280   @ 0
//   masks_ext:  (4,5,128,128) = 327680 @ 1280
//   node_scores:(4,5)         = 20     @ 328960
#define OFF_MASKS 1280
#define OFF_SCORES 328960

__constant__ int c_agidx[4] = {0, 5461, 10922, 16383};

// pack two f32 -> (bf16,bf16) in one uint, RTNE
__device__ __forceinline__ unsigned pack_bf16x2(float x, float y) {
    unsigned ux = __float_as_uint(x);
    unsigned uy = __float_as_uint(y);
    ux = (ux + 0x7fffu + ((ux >> 16) & 1u)) >> 16;          // low 16 = bf16(x)
    uy = (uy + 0x7fffu + ((uy >> 16) & 1u)) & 0xffff0000u;  // high 16 = bf16(y)
    return ux | uy;
}

// ---------- CSR build ----------
__global__ void k_count(const int* __restrict__ edges, const float* __restrict__ wts,
                        int* __restrict__ deg) {
    int idx = blockIdx.x * blockDim.x + threadIdx.x;
    if (idx >= TOTE) return;
    int b = idx >> 17;           // / E_
    int e = idx & (E_ - 1);
    float w = wts[idx];          // (B,E) flat == idx
    if (w > 0.5f) {
        int row = edges[(b * 2) * E_ + e];
        atomicAdd(&deg[row], 1);
    }
}

// ---- parallel scan over padded degrees ----
__global__ __launch_bounds__(256) void k_scan1(const int* __restrict__ deg,
                                               int* __restrict__ blockSums) {
    int i = blockIdx.x * 256 + threadIdx.x;
    int v = (deg[i] + 3) & ~3;
    #pragma unroll
    for (int off = 1; off < 64; off <<= 1) v += __shfl_xor(v, off, 64);
    __shared__ int ws[4];
    int lane = threadIdx.x & 63, w = threadIdx.x >> 6;
    if (lane == 0) ws[w] = v;
    __syncthreads();
    if (threadIdx.x == 0)
        blockSums[blockIdx.x] = ws[0] + ws[1] + ws[2] + ws[3];
}

// each block redundantly scans the 256 block sums, then rescans its 256 rows
__global__ __launch_bounds__(256) void k_scan3(const int* __restrict__ deg,
                                               const int* __restrict__ blockSums,
                                               int* __restrict__ row_start,
                                               int* __restrict__ cursor) {
    int t = threadIdx.x;
    int lane = t & 63, w = t >> 6;
    __shared__ int offs[256];
    __shared__ int wtotA[4];
    __shared__ int wtotB[4];

    int bs = blockSums[t];
    int binc = bs;
    #pragma unroll
    for (int off = 1; off < 64; off <<= 1) {
        int u = __shfl_up(binc, off, 64);
        if (lane >= off) binc += u;
    }
    if (lane == 63) wtotA[w] = binc;
    __syncthreads();
    int badd = 0;
    for (int j = 0; j < w; ++j) badd += wtotA[j];
    offs[t] = binc + badd - bs;        // exclusive prefix of blockSums
    if (blockIdx.x == 0 && t == 255) row_start[BN] = binc + badd;
    __syncthreads();
    int blockOff = offs[blockIdx.x];

    int i = blockIdx.x * 256 + t;
    int v = (deg[i] + 3) & ~3;
    int incl = v;
    #pragma unroll
    for (int off = 1; off < 64; off <<= 1) {
        int u = __shfl_up(incl, off, 64);
        if (lane >= off) incl += u;
    }
    if (lane == 63) wtotB[w] = incl;
    __syncthreads();
    int wadd = 0;
    for (int j = 0; j < w; ++j) wadd += wtotB[j];
    int rs = blockOff + wadd + incl - v;
    row_start[i] = rs;
    cursor[i] = rs;
}

__global__ void k_scatter(const int* __restrict__ edges, const float* __restrict__ wts,
                          int* __restrict__ cursor, int2* __restrict__ cw) {
    int idx = blockIdx.x * blockDim.x + threadIdx.x;
    if (idx >= TOTE) return;
    int b = idx >> 17;
    int e = idx & (E_ - 1);
    float w = wts[idx];
    if (w > 0.5f) {
        int row = edges[(b * 2) * E_ + e];
        int col = edges[(b * 2) * E_ + E_ + e];
        int pos = atomicAdd(&cursor[row], 1);
        cw[pos] = make_int2(col, __float_as_int(w));
    }
}

// Deterministic order within each row's REAL segment: sort by (col, w-bits).
// Also writes the (0,0) padding entries up to the 4-aligned row end.
__global__ void k_sort(const int* __restrict__ row_start, const int* __restrict__ deg,
                       int2* __restrict__ cw) {
    int n = blockIdx.x * blockDim.x + threadIdx.x;
    if (n >= BN) return;
    int s = row_start[n], epos = s + deg[n], pend = row_start[n + 1];
    for (int i = s + 1; i < epos; ++i) {
        int2 v = cw[i];
        unsigned long long key =
            ((unsigned long long)(unsigned)v.x << 32) | (unsigned)v.y;
        int j = i - 1;
        while (j >= s) {
            int2 u = cw[j];
            unsigned long long kj =
                ((unsigned long long)(unsigned)u.x << 32) | (unsigned)u.y;
            if (kj <= key) break;
            cw[j + 1] = u;
            --j;
        }
        cw[j + 1] = v;
    }
    for (int i = epos; i < pend; ++i) cw[i] = make_int2(0, 0);
}

// ---- degree-bucket counting sort via per-block LDS histograms ----
// (perm ordering within a bucket is non-deterministic across blocks, but
//  output bits don't depend on perm: each node's accumulation order is fixed
//  by its own sorted CSR segment; padding replays carry w=0.)
__global__ __launch_bounds__(256) void k_hist(const int* __restrict__ deg,
                                              int* __restrict__ hist) {
    __shared__ int lh[256];
    int t = threadIdx.x;
    lh[t] = 0;
    __syncthreads();
    int n = blockIdx.x * 256 + t;
    int c = (deg[n] + 3) >> 2;
    if (c > 255) c = 255;
    atomicAdd(&lh[c], 1);                    // LDS atomic, block-local
    __syncthreads();
    int cnt = lh[t];
    if (cnt) atomicAdd(&hist[t], cnt);       // ~7 non-empty buckets per block
}

__global__ __launch_bounds__(256) void k_bucketscan(const int* __restrict__ hist,
                                                    int* __restrict__ bucketCur) {
    int t = threadIdx.x;
    int lane = t & 63, w = t >> 6;
    int v = hist[t];
    int incl = v;
    #pragma unroll
    for (int off = 1; off < 64; off <<= 1) {
        int u = __shfl_up(incl, off, 64);
        if (lane >= off) incl += u;
    }
    __shared__ int wtot[4];
    if (lane == 63) wtot[w] = incl;
    __syncthreads();
    int wadd = 0;
    for (int j = 0; j < w; ++j) wadd += wtot[j];
    bucketCur[t] = incl + wadd - v;    // exclusive
}

__global__ __launch_bounds__(256) void k_permscatter(const int* __restrict__ deg,
                                                     int* __restrict__ bucketCur,
                                                     int* __restrict__ perm) {
    __shared__ int lh[256];
    __shared__ int lbase[256];
    int t = threadIdx.x;
    lh[t] = 0;
    __syncthreads();
    int n = blockIdx.x * 256 + t;
    int c = (deg[n] + 3) >> 2;
    if (c > 255) c = 255;
    int lpos = atomicAdd(&lh[c], 1);         // LDS rank within block
    __syncthreads();
    int cnt = lh[t];
    lbase[t] = cnt ? atomicAdd(&bucketCur[t], cnt) : 0;  // one reserve per bucket
    __syncthreads();
    perm[lbase[c] + lpos] = n;
}

// ---------- propagation: FOUR degree-matched nodes per wave ----------
// perm groups nodes of equal chunk count -> 16 gathers in flight with
// near-zero padded replay. Per-node arithmetic bit-exact regardless of
// grouping (padding carries w=0.0; fmaf(0,v,acc)==acc for finite v).
template <bool F32IN>
__global__ __launch_bounds__(256) void k_prop(const void* __restrict__ hin,
                                              unsigned* __restrict__ hout,
                                              const int* __restrict__ row_start,
                                              const int2* __restrict__ cw,
                                              const int* __restrict__ perm) {
    int lane = threadIdx.x & 63;
    int gid = (blockIdx.x << 2) + (threadIdx.x >> 6);   // 0..16383
    int base = __builtin_amdgcn_readfirstlane(gid << 2);
    const int4 p4 = *(const int4*)(perm + base);        // uniform -> s_load
    int u0 = __builtin_amdgcn_readfirstlane(p4.x);
    int u1 = __builtin_amdgcn_readfirstlane(p4.y);
    int u2 = __builtin_amdgcn_readfirstlane(p4.z);
    int u3 = __builtin_amdgcn_readfirstlane(p4.w);
    int s0 = row_start[u0], e0 = row_start[u0 + 1];
    int s1 = row_start[u1], e1 = row_start[u1 + 1];
    int s2 = row_start[u2], e2 = row_start[u2 + 1];
    int s3 = row_start[u3], e3 = row_start[u3 + 1];
    int c0 = (e0 - s0) >> 2, c1 = (e1 - s1) >> 2;
    int c2 = (e2 - s2) >> 2, c3 = (e3 - s3) >> 2;
    int m01 = c0 > c1 ? c0 : c1, m23 = c2 > c3 ? c2 : c3;
    int nmax = m01 > m23 ? m01 : m23;
    int b0 = c0 ? s0 : 0, b1 = c1 ? s1 : 0, b2 = c2 ? s2 : 0, b3 = c3 ? s3 : 0;
    int l0 = (c0 ? c0 : 1) - 1, l1 = (c1 ? c1 : 1) - 1;
    int l2 = (c2 ? c2 : 1) - 1, l3 = (c3 ? c3 : 1) - 1;

    auto gather = [&](int col) -> float2 {
        if constexpr (F32IN) {
            return ((const float2*)hin)[((size_t)col << 6) + lane];
        } else {
            unsigned p = ((const unsigned*)hin)[((size_t)col << 6) + lane];
            float2 r;
            r.x = __uint_as_float(p << 16);
            r.y = __uint_as_float(p & 0xffff0000u);
            return r;
        }
    };

    float ax0 = 0.f, ay0 = 0.f, ax1 = 0.f, ay1 = 0.f;
    float ax2 = 0.f, ay2 = 0.f, ax3 = 0.f, ay3 = 0.f;
    for (int j = 0; j < nmax; ++j) {
        int j0 = j < l0 ? j : l0, j1 = j < l1 ? j : l1;
        int j2 = j < l2 ? j : l2, j3 = j < l3 ? j : l3;
        const int4* q0 = (const int4*)(cw + b0 + (j0 << 2));
        const int4* q1 = (const int4*)(cw + b1 + (j1 << 2));
        const int4* q2 = (const int4*)(cw + b2 + (j2 << 2));
        const int4* q3 = (const int4*)(cw + b3 + (j3 << 2));
        int4 a0 = q0[0], a1 = q0[1];
        int4 a2 = q1[0], a3 = q1[1];
        int4 a4 = q2[0], a5 = q2[1];
        int4 a6 = q3[0], a7 = q3[1];
        // 16 gathers in flight
        float2 v00 = gather(a0.x), v01 = gather(a0.z);
        float2 v02 = gather(a1.x), v03 = gather(a1.z);
        float2 v10 = gather(a2.x), v11 = gather(a2.z);
        float2 v12 = gather(a3.x), v13 = gather(a3.z);
        float2 v20 = gather(a4.x), v21 = gather(a4.z);
        float2 v22 = gather(a5.x), v23 = gather(a5.z);
        float2 v30 = gather(a6.x), v31 = gather(a6.z);
        float2 v32 = gather(a7.x), v33 = gather(a7.z);
        bool k0 = j < c0, k1 = j < c1, k2 = j < c2, k3 = j < c3;
        float w00 = k0 ? __int_as_float(a0.y) : 0.f;
        float w01 = k0 ? __int_as_float(a0.w) : 0.f;
        float w02 = k0 ? __int_as_float(a1.y) : 0.f;
        float w03 = k0 ? __int_as_float(a1.w) : 0.f;
        float w10 = k1 ? __int_as_float(a2.y) : 0.f;
        float w11 = k1 ? __int_as_float(a2.w) : 0.f;
        float w12 = k1 ? __int_as_float(a3.y) : 0.f;
        float w13 = k1 ? __int_as_float(a3.w) : 0.f;
        float w20 = k2 ? __int_as_float(a4.y) : 0.f;
        float w21 = k2 ? __int_as_float(a4.w) : 0.f;
        float w22 = k2 ? __int_as_float(a5.y) : 0.f;
        float w23 = k2 ? __int_as_float(a5.w) : 0.f;
        float w30 = k3 ? __int_as_float(a6.y) : 0.f;
        float w31 = k3 ? __int_as_float(a6.w) : 0.f;
        float w32 = k3 ? __int_as_float(a7.y) : 0.f;
        float w33 = k3 ? __int_as_float(a7.w) : 0.f;
        ax0 = fmaf(w00, v00.x, ax0); ay0 = fmaf(w00, v00.y, ay0);
        ax0 = fmaf(w01, v01.x, ax0); ay0 = fmaf(w01, v01.y, ay0);
        ax0 = fmaf(w02, v02.x, ax0); ay0 = fmaf(w02, v02.y, ay0);
        ax0 = fmaf(w03, v03.x, ax0); ay0 = fmaf(w03, v03.y, ay0);
        ax1 = fmaf(w10, v10.x, ax1); ay1 = fmaf(w10, v10.y, ay1);
        ax1 = fmaf(w11, v11.x, ax1); ay1 = fmaf(w11, v11.y, ay1);
        ax1 = fmaf(w12, v12.x, ax1); ay1 = fmaf(w12, v12.y, ay1);
        ax1 = fmaf(w13, v13.x, ax1); ay1 = fmaf(w13, v13.y, ay1);
        ax2 = fmaf(w20, v20.x, ax2); ay2 = fmaf(w20, v20.y, ay2);
        ax2 = fmaf(w21, v21.x, ax2); ay2 = fmaf(w21, v21.y, ay2);
        ax2 = fmaf(w22, v22.x, ax2); ay2 = fmaf(w22, v22.y, ay2);
        ax2 = fmaf(w23, v23.x, ax2); ay2 = fmaf(w23, v23.y, ay2);
        ax3 = fmaf(w30, v30.x, ax3); ay3 = fmaf(w30, v30.y, ay3);
        ax3 = fmaf(w31, v31.x, ax3); ay3 = fmaf(w31, v31.y, ay3);
        ax3 = fmaf(w32, v32.x, ax3); ay3 = fmaf(w32, v32.y, ay3);
        ax3 = fmaf(w33, v33.x, ax3); ay3 = fmaf(w33, v33.y, ay3);
    }
    float ss0 = ax0 * ax0 + ay0 * ay0;
    float ss1 = ax1 * ax1 + ay1 * ay1;
    float ss2 = ax2 * ax2 + ay2 * ay2;
    float ss3 = ax3 * ax3 + ay3 * ay3;
    #pragma unroll
    for (int off = 32; off; off >>= 1) {
        ss0 += __shfl_xor(ss0, off, 64);
        ss1 += __shfl_xor(ss1, off, 64);
        ss2 += __shfl_xor(ss2, off, 64);
        ss3 += __shfl_xor(ss3, off, 64);
    }
    float i0 = 1.0f / (sqrtf(ss0) + 1e-8f);
    float i1 = 1.0f / (sqrtf(ss1) + 1e-8f);
    float i2 = 1.0f / (sqrtf(ss2) + 1e-8f);
    float i3 = 1.0f / (sqrtf(ss3) + 1e-8f);
    hout[((size_t)u0 << 6) + lane] = pack_bf16x2(ax0 * i0, ay0 * i0);
    hout[((size_t)u1 << 6) + lane] = pack_bf16x2(ax1 * i1, ay1 * i1);
    hout[((size_t)u2 << 6) + lane] = pack_bf16x2(ax2 * i2, ay2 * i2);
    hout[((size_t)u3 << 6) + lane] = pack_bf16x2(ax3 * i3, ay3 * i3);
}

// ---------- competition: wave per row (bf16 h) ----------
__global__ __launch_bounds__(256) void k_masks(const unsigned* __restrict__ h,
                                               float* __restrict__ masks) {
    int wave = threadIdx.x >> 6;
    int lane = threadIdx.x & 63;
    int n = blockIdx.x * 4 + wave;      // global row 0..65535
    int b = n >> 14;
    int nl = n & (N_ - 1);
    unsigned vp = h[((size_t)n << 6) + lane];
    float vx = __uint_as_float(vp << 16);
    float vy = __uint_as_float(vp & 0xffff0000u);
    float dot[4];
    #pragma unroll
    for (int m = 0; m < 4; ++m) {
        int an = b * N_ + c_agidx[m];
        unsigned ap = h[((size_t)an << 6) + lane];
        float axx = __uint_as_float(ap << 16);
        float ayy = __uint_as_float(ap & 0xffff0000u);
        float d = vx * axx + vy * ayy;
        #pragma unroll
        for (int off = 32; off; off >>= 1) d += __shfl_xor(d, off, 64);
        dot[m] = d;
    }
    const float scl = 0.0883883476483184405501055452631f; // 1/sqrt(128)
    float l0 = dot[0] * scl, l1 = dot[1] * scl, l2 = dot[2] * scl, l3 = dot[3] * scl;
    float mx = fmaxf(fmaxf(fmaxf(l0, l1), fmaxf(l2, l3)), 0.f);
    float e0 = expf(l0 - mx), e1 = expf(l1 - mx), e2 = expf(l2 - mx),
          e3 = expf(l3 - mx), e4 = expf(0.f - mx);
    float den = e0 + e1 + e2 + e3 + e4;
    if (lane < 5) {
        float p = (lane == 0) ? e0 : (lane == 1) ? e1 : (lane == 2) ? e2
                  : (lane == 3) ? e3 : e4;
        masks[((size_t)b * 5 + lane) * N_ + nl] = p / den;
    }
}

// ---------- nf partials + chunk maxes: ONE feat pass for all 5 masks ----------
// grid: 4 b x 64 chunks; each block covers 256 rows, all 5 m-channels
__global__ __launch_bounds__(256) void k_nfpart(const float* __restrict__ feat,
                                                const float* __restrict__ masks,
                                                float* __restrict__ part,
                                                float* __restrict__ maxpart) {
    int b = blockIdx.x >> 6;
    int chunk = blockIdx.x & 63;
    int d = threadIdx.x & 63;
    int g = threadIdx.x >> 6;   // wave id 0..3
    int n0 = chunk * 256 + g * 64;
    const float* fb = feat + (size_t)b * N_ * D_;
    float acc[5] = {0.f, 0.f, 0.f, 0.f, 0.f};
    float mxv[5] = {-1e30f, -1e30f, -1e30f, -1e30f, -1e30f};
    for (int i = 0; i < 64; ++i) {
        int n = n0 + i;
        float fv = fb[(size_t)n * D_ + d];
        #pragma unroll
        for (int m = 0; m < 5; ++m) {
            float mv = masks[((size_t)b * 5 + m) * N_ + n];  // uniform -> s_load
            acc[m] = fmaf(fv, mv, acc[m]);
            mxv[m] = fmaxf(mxv[m], mv);
        }
    }
    __shared__ float lds[4][5][64];
    __shared__ float lmx[4][5];
    #pragma unroll
    for (int m = 0; m < 5; ++m) lds[g][m][d] = acc[m];
    if (d == 0) {
        #pragma unroll
        for (int m = 0; m < 5; ++m) lmx[g][m] = mxv[m];
    }
    __syncthreads();
    if (g == 0) {
        #pragma unroll
        for (int m = 0; m < 5; ++m) {
            float s = lds[0][m][d] + lds[1][m][d] + lds[2][m][d] + lds[3][m][d];
            part[(((size_t)b * 64 + chunk) * 5 + m) * 64 + d] = s;
            if (d == 0)
                maxpart[((size_t)b * 64 + chunk) * 5 + m] =
                    fmaxf(fmaxf(lmx[0][m], lmx[1][m]), fmaxf(lmx[2][m], lmx[3][m]));
        }
    }
}

// ---------- final: sum chunks, normalize over m-axis, scores ----------
__global__ void k_nffinal(const float* __restrict__ part, const float* __restrict__ maxpart,
                          float* __restrict__ out) {
    int b = blockIdx.x;     // 4 blocks
    int d = threadIdx.x;    // 64 threads
    float v[5];
    float ss = 0.f;
    for (int m = 0; m < 5; ++m) {
        float s = 0.f;
        for (int c = 0; c < 64; ++c)
            s += part[(((size_t)b * 64 + c) * 5 + m) * 64 + d];
        v[m] = s;
        ss += s * s;
    }
    float nrm = fmaxf(sqrtf(ss), 1e-12f);
    for (int m = 0; m < 5; ++m) out[((size_t)b * 5 + m) * 64 + d] = v[m] / nrm;
    if (d < 5) {
        float mx = -1e30f;
        for (int c = 0; c < 64; ++c)
            mx = fmaxf(mx, maxpart[((size_t)b * 64 + c) * 5 + d]);
        out[OFF_SCORES + b * 5 + d] = mx;
    }
}

extern "C" void kernel_launch(void* const* d_in, const int* in_sizes, int n_in,
                              void* d_out, int out_size, void* d_ws, size_t ws_size,
                              hipStream_t stream) {
    const float* feat  = (const float*)d_in[0];   // (4,16384,64)
    const int*   edges = (const int*)d_in[1];     // (4,2,131072)
    const float* wts   = (const float*)d_in[2];   // (4,131072)
    const float* init  = (const float*)d_in[3];   // (4,16384,128)
    float* out = (float*)d_out;

    // workspace layout (bf16 h: 65536 rows x 64 uints = 16 MB each)
    unsigned* hA = (unsigned*)d_ws;
    unsigned* hB = hA + (size_t)BN * 64;
    int* row_start  = (int*)(hB + (size_t)BN * 64);   // 65537 (+pad)
    int* cursor     = row_start + 65544;              // 65536
    int* deg        = cursor + BN;                    // 65536
    int* hist       = deg + BN;                       // 256 (memset with deg)
    int* blockSums  = hist + 256;                     // 256
    int* bucketCur  = blockSums + 256;                // 256
    int* perm       = bucketCur + 256;                // 65536
    int2* cw        = (int2*)(perm + BN);             // PAD_CAP int2 (~5.8 MB)
    float* part     = (float*)(cw + PAD_CAP);         // 4*64*5*64 = 81920
    float* maxpart  = part + 81920;                   // 1280

    // CSR build (padded rows, interleaved (col,w) pairs; padding written by k_sort)
    hipMemsetAsync(deg, 0, (BN + 256) * sizeof(int), stream);   // deg + hist
    k_count<<<TOTE / 256, 256, 0, stream>>>(edges, wts, deg);
    k_scan1<<<256, 256, 0, stream>>>(deg, blockSums);
    k_scan3<<<256, 256, 0, stream>>>(deg, blockSums, row_start, cursor);
    k_scatter<<<TOTE / 256, 256, 0, stream>>>(edges, wts, cursor, cw);
    k_sort<<<BN / 256, 256, 0, stream>>>(row_start, deg, cw);
    // degree-bucket grouping permutation (LDS-histogram, low atomic contention)
    k_hist<<<BN / 256, 256, 0, stream>>>(deg, hist);
    k_bucketscan<<<1, 256, 0, stream>>>(hist, bucketCur);
    k_permscatter<<<BN / 256, 256, 0, stream>>>(deg, bucketCur, perm);

    // 25 propagation iterations; iter 0 reads f32 init directly
    k_prop<true><<<BN / 16, 256, 0, stream>>>(init, hA, row_start, cw, perm);
    const unsigned* src = hA;
    for (int it = 1; it < ITERS; ++it) {
        unsigned* dst = (it & 1) ? hB : hA;
        k_prop<false><<<BN / 16, 256, 0, stream>>>(src, dst, row_start, cw, perm);
        src = dst;
    }

    // competition + outputs
    k_masks<<<BN / 4, 256, 0, stream>>>(src, out + OFF_MASKS);
    k_nfpart<<<4 * 64, 256, 0, stream>>>(feat, out + OFF_MASKS, part, maxpart);
    k_nffinal<<<4, 64, 0, stream>>>(part, maxpart, out);
}

// Round 9
// 558.199 us; speedup vs baseline: 2.8504x; 1.0097x over previous
//
#include <hip/hip_runtime.h>

// Problem constants
#define B_    4
#define N_    16384
#define D_    64
#define Q_    128
#define E_    131072
#define M_    4
#define BN    65536        // B*N
#define TOTE  524288       // B*E
#define ITERS 25
#define PAD_CAP (TOTE + 3 * BN + 64)   // padded-CSR capacity (edges)

// Output layout (f32, concatenated flat):
//   nf:         (4,5,64)      = 1280   @ 0
//   masks_ext:  (4,5,128,128) = 327680 @ 1280
//   node_scores:(4,5)         = 20     @ 328960
#define OFF_MASKS 1280
#define OFF_SCORES 328960

__constant__ int c_agidx[4] = {0, 5461, 10922, 16383};

// pack two f32 -> (bf16,bf16) in one uint, RTNE
__device__ __forceinline__ unsigned pack_bf16x2(float x, float y) {
    unsigned ux = __float_as_uint(x);
    unsigned uy = __float_as_uint(y);
    ux = (ux + 0x7fffu + ((ux >> 16) & 1u)) >> 16;          // low 16 = bf16(x)
    uy = (uy + 0x7fffu + ((uy >> 16) & 1u)) & 0xffff0000u;  // high 16 = bf16(y)
    return ux | uy;
}

// ---------- CSR build ----------
__global__ void k_count(const int* __restrict__ edges, const float* __restrict__ wts,
                        int* __restrict__ deg) {
    int idx = blockIdx.x * blockDim.x + threadIdx.x;
    if (idx >= TOTE) return;
    int b = idx >> 17;           // / E_
    int e = idx & (E_ - 1);
    float w = wts[idx];          // (B,E) flat == idx
    if (w > 0.5f) {
        int row = edges[(b * 2) * E_ + e];
        atomicAdd(&deg[row], 1);
    }
}

// ---- parallel scan over padded degrees (original node order) ----
__global__ __launch_bounds__(256) void k_scan1(const int* __restrict__ deg,
                                               int* __restrict__ blockSums) {
    int i = blockIdx.x * 256 + threadIdx.x;
    int v = (deg[i] + 3) & ~3;
    #pragma unroll
    for (int off = 1; off < 64; off <<= 1) v += __shfl_xor(v, off, 64);
    __shared__ int ws[4];
    int lane = threadIdx.x & 63, w = threadIdx.x >> 6;
    if (lane == 0) ws[w] = v;
    __syncthreads();
    if (threadIdx.x == 0)
        blockSums[blockIdx.x] = ws[0] + ws[1] + ws[2] + ws[3];
}

__global__ __launch_bounds__(256) void k_scan3(const int* __restrict__ deg,
                                               const int* __restrict__ blockSums,
                                               int* __restrict__ row_start,
                                               int* __restrict__ cursor) {
    int t = threadIdx.x;
    int lane = t & 63, w = t >> 6;
    __shared__ int offs[256];
    __shared__ int wtotA[4];
    __shared__ int wtotB[4];

    int bs = blockSums[t];
    int binc = bs;
    #pragma unroll
    for (int off = 1; off < 64; off <<= 1) {
        int u = __shfl_up(binc, off, 64);
        if (lane >= off) binc += u;
    }
    if (lane == 63) wtotA[w] = binc;
    __syncthreads();
    int badd = 0;
    for (int j = 0; j < w; ++j) badd += wtotA[j];
    offs[t] = binc + badd - bs;
    if (blockIdx.x == 0 && t == 255) row_start[BN] = binc + badd;
    __syncthreads();
    int blockOff = offs[blockIdx.x];

    int i = blockIdx.x * 256 + t;
    int v = (deg[i] + 3) & ~3;
    int incl = v;
    #pragma unroll
    for (int off = 1; off < 64; off <<= 1) {
        int u = __shfl_up(incl, off, 64);
        if (lane >= off) incl += u;
    }
    if (lane == 63) wtotB[w] = incl;
    __syncthreads();
    int wadd = 0;
    for (int j = 0; j < w; ++j) wadd += wtotB[j];
    int rs = blockOff + wadd + incl - v;
    row_start[i] = rs;
    cursor[i] = rs;
}

__global__ void k_scatter(const int* __restrict__ edges, const float* __restrict__ wts,
                          int* __restrict__ cursor, int2* __restrict__ cw) {
    int idx = blockIdx.x * blockDim.x + threadIdx.x;
    if (idx >= TOTE) return;
    int b = idx >> 17;
    int e = idx & (E_ - 1);
    float w = wts[idx];
    if (w > 0.5f) {
        int row = edges[(b * 2) * E_ + e];
        int col = edges[(b * 2) * E_ + E_ + e];
        int pos = atomicAdd(&cursor[row], 1);
        cw[pos] = make_int2(col, __float_as_int(w));
    }
}

// Deterministic order within each row's REAL segment: sort by (col, w-bits).
// Also writes the (0,0) padding entries up to the 4-aligned row end.
__global__ void k_sort(const int* __restrict__ row_start, const int* __restrict__ deg,
                       int2* __restrict__ cw) {
    int n = blockIdx.x * blockDim.x + threadIdx.x;
    if (n >= BN) return;
    int s = row_start[n], epos = s + deg[n], pend = row_start[n + 1];
    for (int i = s + 1; i < epos; ++i) {
        int2 v = cw[i];
        unsigned long long key =
            ((unsigned long long)(unsigned)v.x << 32) | (unsigned)v.y;
        int j = i - 1;
        while (j >= s) {
            int2 u = cw[j];
            unsigned long long kj =
                ((unsigned long long)(unsigned)u.x << 32) | (unsigned)u.y;
            if (kj <= key) break;
            cw[j + 1] = u;
            --j;
        }
        cw[j + 1] = v;
    }
    for (int i = epos; i < pend; ++i) cw[i] = make_int2(0, 0);
}

// ---- degree-bucket counting sort via per-block LDS histograms ----
// (perm order is non-deterministic across blocks; output bits don't depend
//  on it: per-row accumulation order is fixed by the sorted CSR segment.)
__global__ __launch_bounds__(256) void k_hist(const int* __restrict__ deg,
                                              int* __restrict__ hist) {
    __shared__ int lh[256];
    int t = threadIdx.x;
    lh[t] = 0;
    __syncthreads();
    int n = blockIdx.x * 256 + t;
    int c = (deg[n] + 3) >> 2;
    if (c > 255) c = 255;
    atomicAdd(&lh[c], 1);
    __syncthreads();
    int cnt = lh[t];
    if (cnt) atomicAdd(&hist[t], cnt);
}

__global__ __launch_bounds__(256) void k_bucketscan(const int* __restrict__ hist,
                                                    int* __restrict__ bucketCur) {
    int t = threadIdx.x;
    int lane = t & 63, w = t >> 6;
    int v = hist[t];
    int incl = v;
    #pragma unroll
    for (int off = 1; off < 64; off <<= 1) {
        int u = __shfl_up(incl, off, 64);
        if (lane >= off) incl += u;
    }
    __shared__ int wtot[4];
    if (lane == 63) wtot[w] = incl;
    __syncthreads();
    int wadd = 0;
    for (int j = 0; j < w; ++j) wadd += wtot[j];
    bucketCur[t] = incl + wadd - v;
}

__global__ __launch_bounds__(256) void k_permscatter(const int* __restrict__ deg,
                                                     int* __restrict__ bucketCur,
                                                     int* __restrict__ perm) {
    __shared__ int lh[256];
    __shared__ int lbase[256];
    int t = threadIdx.x;
    lh[t] = 0;
    __syncthreads();
    int n = blockIdx.x * 256 + t;
    int c = (deg[n] + 3) >> 2;
    if (c > 255) c = 255;
    int lpos = atomicAdd(&lh[c], 1);
    __syncthreads();
    int cnt = lh[t];
    lbase[t] = cnt ? atomicAdd(&bucketCur[t], cnt) : 0;
    __syncthreads();
    perm[lbase[c] + lpos] = n;
}

// ---- scan of padded degrees in PERM order -> prow ----
__global__ __launch_bounds__(256) void k_pscan1(const int* __restrict__ deg,
                                                const int* __restrict__ perm,
                                                int* __restrict__ blockSums2) {
    int i = blockIdx.x * 256 + threadIdx.x;
    int v = (deg[perm[i]] + 3) & ~3;
    #pragma unroll
    for (int off = 1; off < 64; off <<= 1) v += __shfl_xor(v, off, 64);
    __shared__ int ws[4];
    int lane = threadIdx.x & 63, w = threadIdx.x >> 6;
    if (lane == 0) ws[w] = v;
    __syncthreads();
    if (threadIdx.x == 0)
        blockSums2[blockIdx.x] = ws[0] + ws[1] + ws[2] + ws[3];
}

__global__ __launch_bounds__(256) void k_pscan3(const int* __restrict__ deg,
                                                const int* __restrict__ perm,
                                                const int* __restrict__ blockSums2,
                                                int* __restrict__ prow) {
    int t = threadIdx.x;
    int lane = t & 63, w = t >> 6;
    __shared__ int offs[256];
    __shared__ int wtotA[4];
    __shared__ int wtotB[4];

    int bs = blockSums2[t];
    int binc = bs;
    #pragma unroll
    for (int off = 1; off < 64; off <<= 1) {
        int u = __shfl_up(binc, off, 64);
        if (lane >= off) binc += u;
    }
    if (lane == 63) wtotA[w] = binc;
    __syncthreads();
    int badd = 0;
    for (int j = 0; j < w; ++j) badd += wtotA[j];
    offs[t] = binc + badd - bs;
    if (blockIdx.x == 0 && t == 255) prow[BN] = binc + badd;
    __syncthreads();
    int blockOff = offs[blockIdx.x];

    int i = blockIdx.x * 256 + t;
    int v = (deg[perm[i]] + 3) & ~3;
    int incl = v;
    #pragma unroll
    for (int off = 1; off < 64; off <<= 1) {
        int u = __shfl_up(incl, off, 64);
        if (lane >= off) incl += u;
    }
    if (lane == 63) wtotB[w] = incl;
    __syncthreads();
    int wadd = 0;
    for (int j = 0; j < w; ++j) wadd += wtotB[j];
    prow[i] = blockOff + wadd + incl - v;
}

// ---- copy each node's padded (sorted) segment into perm-order layout ----
__global__ __launch_bounds__(256) void k_copy(const int* __restrict__ row_start,
                                              const int* __restrict__ prow,
                                              const int* __restrict__ perm,
                                              const int* __restrict__ deg,
                                              const int2* __restrict__ cw,
                                              int2* __restrict__ cw2) {
    int i = blockIdx.x * 256 + threadIdx.x;
    int n = perm[i];
    int src = row_start[n];
    int dst = prow[i];
    int nq = (deg[n] + 3) >> 2;          // 4-edge quads
    for (int j = 0; j < nq; ++j) {
        const int4* s = (const int4*)(cw + src + (j << 2));
        int4* d = (int4*)(cw2 + dst + (j << 2));
        int4 x0 = s[0], x1 = s[1];
        d[0] = x0; d[1] = x1;
    }
}

// ---------- propagation: FOUR degree-matched nodes per wave ----------
// cw2 is perm-ordered: wave g consumes the CONTIGUOUS range
// cw2[prow[4g] .. prow[4g+4]) -> sequential chunk streaming + 16 gathers
// in flight + near-zero padded replay. Bit-exact per node regardless of
// grouping (padding carries w=0.0).
template <bool F32IN>
__global__ __launch_bounds__(256) void k_prop(const void* __restrict__ hin,
                                              unsigned* __restrict__ hout,
                                              const int* __restrict__ prow,
                                              const int2* __restrict__ cw,
                                              const int* __restrict__ perm) {
    int lane = threadIdx.x & 63;
    int gid = (blockIdx.x << 2) + (threadIdx.x >> 6);   // 0..16383
    int base = __builtin_amdgcn_readfirstlane(gid << 2);
    const int4 p4 = *(const int4*)(perm + base);        // uniform -> s_load
    int u0 = __builtin_amdgcn_readfirstlane(p4.x);
    int u1 = __builtin_amdgcn_readfirstlane(p4.y);
    int u2 = __builtin_amdgcn_readfirstlane(p4.z);
    int u3 = __builtin_amdgcn_readfirstlane(p4.w);
    int s0 = prow[base], s1 = prow[base + 1], s2 = prow[base + 2],
        s3 = prow[base + 3], e3 = prow[base + 4];       // contiguous s_loads
    int c0 = (s1 - s0) >> 2, c1 = (s2 - s1) >> 2;
    int c2 = (s3 - s2) >> 2, c3 = (e3 - s3) >> 2;
    int m01 = c0 > c1 ? c0 : c1, m23 = c2 > c3 ? c2 : c3;
    int nmax = m01 > m23 ? m01 : m23;
    int b0 = c0 ? s0 : 0, b1 = c1 ? s1 : 0, b2 = c2 ? s2 : 0, b3 = c3 ? s3 : 0;
    int l0 = (c0 ? c0 : 1) - 1, l1 = (c1 ? c1 : 1) - 1;
    int l2 = (c2 ? c2 : 1) - 1, l3 = (c3 ? c3 : 1) - 1;

    auto gather = [&](int col) -> float2 {
        if constexpr (F32IN) {
            return ((const float2*)hin)[((size_t)col << 6) + lane];
        } else {
            unsigned p = ((const unsigned*)hin)[((size_t)col << 6) + lane];
            float2 r;
            r.x = __uint_as_float(p << 16);
            r.y = __uint_as_float(p & 0xffff0000u);
            return r;
        }
    };

    float ax0 = 0.f, ay0 = 0.f, ax1 = 0.f, ay1 = 0.f;
    float ax2 = 0.f, ay2 = 0.f, ax3 = 0.f, ay3 = 0.f;
    for (int j = 0; j < nmax; ++j) {
        int j0 = j < l0 ? j : l0, j1 = j < l1 ? j : l1;
        int j2 = j < l2 ? j : l2, j3 = j < l3 ? j : l3;
        const int4* q0 = (const int4*)(cw + b0 + (j0 << 2));
        const int4* q1 = (const int4*)(cw + b1 + (j1 << 2));
        const int4* q2 = (const int4*)(cw + b2 + (j2 << 2));
        const int4* q3 = (const int4*)(cw + b3 + (j3 << 2));
        int4 a0 = q0[0], a1 = q0[1];
        int4 a2 = q1[0], a3 = q1[1];
        int4 a4 = q2[0], a5 = q2[1];
        int4 a6 = q3[0], a7 = q3[1];
        // 16 gathers in flight
        float2 v00 = gather(a0.x), v01 = gather(a0.z);
        float2 v02 = gather(a1.x), v03 = gather(a1.z);
        float2 v10 = gather(a2.x), v11 = gather(a2.z);
        float2 v12 = gather(a3.x), v13 = gather(a3.z);
        float2 v20 = gather(a4.x), v21 = gather(a4.z);
        float2 v22 = gather(a5.x), v23 = gather(a5.z);
        float2 v30 = gather(a6.x), v31 = gather(a6.z);
        float2 v32 = gather(a7.x), v33 = gather(a7.z);
        bool k0 = j < c0, k1 = j < c1, k2 = j < c2, k3 = j < c3;
        float w00 = k0 ? __int_as_float(a0.y) : 0.f;
        float w01 = k0 ? __int_as_float(a0.w) : 0.f;
        float w02 = k0 ? __int_as_float(a1.y) : 0.f;
        float w03 = k0 ? __int_as_float(a1.w) : 0.f;
        float w10 = k1 ? __int_as_float(a2.y) : 0.f;
        float w11 = k1 ? __int_as_float(a2.w) : 0.f;
        float w12 = k1 ? __int_as_float(a3.y) : 0.f;
        float w13 = k1 ? __int_as_float(a3.w) : 0.f;
        float w20 = k2 ? __int_as_float(a4.y) : 0.f;
        float w21 = k2 ? __int_as_float(a4.w) : 0.f;
        float w22 = k2 ? __int_as_float(a5.y) : 0.f;
        float w23 = k2 ? __int_as_float(a5.w) : 0.f;
        float w30 = k3 ? __int_as_float(a6.y) : 0.f;
        float w31 = k3 ? __int_as_float(a6.w) : 0.f;
        float w32 = k3 ? __int_as_float(a7.y) : 0.f;
        float w33 = k3 ? __int_as_float(a7.w) : 0.f;
        ax0 = fmaf(w00, v00.x, ax0); ay0 = fmaf(w00, v00.y, ay0);
        ax0 = fmaf(w01, v01.x, ax0); ay0 = fmaf(w01, v01.y, ay0);
        ax0 = fmaf(w02, v02.x, ax0); ay0 = fmaf(w02, v02.y, ay0);
        ax0 = fmaf(w03, v03.x, ax0); ay0 = fmaf(w03, v03.y, ay0);
        ax1 = fmaf(w10, v10.x, ax1); ay1 = fmaf(w10, v10.y, ay1);
        ax1 = fmaf(w11, v11.x, ax1); ay1 = fmaf(w11, v11.y, ay1);
        ax1 = fmaf(w12, v12.x, ax1); ay1 = fmaf(w12, v12.y, ay1);
        ax1 = fmaf(w13, v13.x, ax1); ay1 = fmaf(w13, v13.y, ay1);
        ax2 = fmaf(w20, v20.x, ax2); ay2 = fmaf(w20, v20.y, ay2);
        ax2 = fmaf(w21, v21.x, ax2); ay2 = fmaf(w21, v21.y, ay2);
        ax2 = fmaf(w22, v22.x, ax2); ay2 = fmaf(w22, v22.y, ay2);
        ax2 = fmaf(w23, v23.x, ax2); ay2 = fmaf(w23, v23.y, ay2);
        ax3 = fmaf(w30, v30.x, ax3); ay3 = fmaf(w30, v30.y, ay3);
        ax3 = fmaf(w31, v31.x, ax3); ay3 = fmaf(w31, v31.y, ay3);
        ax3 = fmaf(w32, v32.x, ax3); ay3 = fmaf(w32, v32.y, ay3);
        ax3 = fmaf(w33, v33.x, ax3); ay3 = fmaf(w33, v33.y, ay3);
    }
    float ss0 = ax0 * ax0 + ay0 * ay0;
    float ss1 = ax1 * ax1 + ay1 * ay1;
    float ss2 = ax2 * ax2 + ay2 * ay2;
    float ss3 = ax3 * ax3 + ay3 * ay3;
    #pragma unroll
    for (int off = 32; off; off >>= 1) {
        ss0 += __shfl_xor(ss0, off, 64);
        ss1 += __shfl_xor(ss1, off, 64);
        ss2 += __shfl_xor(ss2, off, 64);
        ss3 += __shfl_xor(ss3, off, 64);
    }
    float i0 = 1.0f / (sqrtf(ss0) + 1e-8f);
    float i1 = 1.0f / (sqrtf(ss1) + 1e-8f);
    float i2 = 1.0f / (sqrtf(ss2) + 1e-8f);
    float i3 = 1.0f / (sqrtf(ss3) + 1e-8f);
    hout[((size_t)u0 << 6) + lane] = pack_bf16x2(ax0 * i0, ay0 * i0);
    hout[((size_t)u1 << 6) + lane] = pack_bf16x2(ax1 * i1, ay1 * i1);
    hout[((size_t)u2 << 6) + lane] = pack_bf16x2(ax2 * i2, ay2 * i2);
    hout[((size_t)u3 << 6) + lane] = pack_bf16x2(ax3 * i3, ay3 * i3);
}

// ---------- competition: wave per row (bf16 h) ----------
__global__ __launch_bounds__(256) void k_masks(const unsigned* __restrict__ h,
                                               float* __restrict__ masks) {
    int wave = threadIdx.x >> 6;
    int lane = threadIdx.x & 63;
    int n = blockIdx.x * 4 + wave;      // global row 0..65535
    int b = n >> 14;
    int nl = n & (N_ - 1);
    unsigned vp = h[((size_t)n << 6) + lane];
    float vx = __uint_as_float(vp << 16);
    float vy = __uint_as_float(vp & 0xffff0000u);
    float dot[4];
    #pragma unroll
    for (int m = 0; m < 4; ++m) {
        int an = b * N_ + c_agidx[m];
        unsigned ap = h[((size_t)an << 6) + lane];
        float axx = __uint_as_float(ap << 16);
        float ayy = __uint_as_float(ap & 0xffff0000u);
        float d = vx * axx + vy * ayy;
        #pragma unroll
        for (int off = 32; off; off >>= 1) d += __shfl_xor(d, off, 64);
        dot[m] = d;
    }
    const float scl = 0.0883883476483184405501055452631f; // 1/sqrt(128)
    float l0 = dot[0] * scl, l1 = dot[1] * scl, l2 = dot[2] * scl, l3 = dot[3] * scl;
    float mx = fmaxf(fmaxf(fmaxf(l0, l1), fmaxf(l2, l3)), 0.f);
    float e0 = expf(l0 - mx), e1 = expf(l1 - mx), e2 = expf(l2 - mx),
          e3 = expf(l3 - mx), e4 = expf(0.f - mx);
    float den = e0 + e1 + e2 + e3 + e4;
    if (lane < 5) {
        float p = (lane == 0) ? e0 : (lane == 1) ? e1 : (lane == 2) ? e2
                  : (lane == 3) ? e3 : e4;
        masks[((size_t)b * 5 + lane) * N_ + nl] = p / den;
    }
}

// ---------- nf partials + chunk maxes: ONE feat pass for all 5 masks ----------
__global__ __launch_bounds__(256) void k_nfpart(const float* __restrict__ feat,
                                                const float* __restrict__ masks,
                                                float* __restrict__ part,
                                                float* __restrict__ maxpart) {
    int b = blockIdx.x >> 6;
    int chunk = blockIdx.x & 63;
    int d = threadIdx.x & 63;
    int g = threadIdx.x >> 6;   // wave id 0..3
    int n0 = chunk * 256 + g * 64;
    const float* fb = feat + (size_t)b * N_ * D_;
    float acc[5] = {0.f, 0.f, 0.f, 0.f, 0.f};
    float mxv[5] = {-1e30f, -1e30f, -1e30f, -1e30f, -1e30f};
    for (int i = 0; i < 64; ++i) {
        int n = n0 + i;
        float fv = fb[(size_t)n * D_ + d];
        #pragma unroll
        for (int m = 0; m < 5; ++m) {
            float mv = masks[((size_t)b * 5 + m) * N_ + n];
            acc[m] = fmaf(fv, mv, acc[m]);
            mxv[m] = fmaxf(mxv[m], mv);
        }
    }
    __shared__ float lds[4][5][64];
    __shared__ float lmx[4][5];
    #pragma unroll
    for (int m = 0; m < 5; ++m) lds[g][m][d] = acc[m];
    if (d == 0) {
        #pragma unroll
        for (int m = 0; m < 5; ++m) lmx[g][m] = mxv[m];
    }
    __syncthreads();
    if (g == 0) {
        #pragma unroll
        for (int m = 0; m < 5; ++m) {
            float s = lds[0][m][d] + lds[1][m][d] + lds[2][m][d] + lds[3][m][d];
            part[(((size_t)b * 64 + chunk) * 5 + m) * 64 + d] = s;
            if (d == 0)
                maxpart[((size_t)b * 64 + chunk) * 5 + m] =
                    fmaxf(fmaxf(lmx[0][m], lmx[1][m]), fmaxf(lmx[2][m], lmx[3][m]));
        }
    }
}

// ---------- final: sum chunks, normalize over m-axis, scores ----------
__global__ void k_nffinal(const float* __restrict__ part, const float* __restrict__ maxpart,
                          float* __restrict__ out) {
    int b = blockIdx.x;     // 4 blocks
    int d = threadIdx.x;    // 64 threads
    float v[5];
    float ss = 0.f;
    for (int m = 0; m < 5; ++m) {
        float s = 0.f;
        for (int c = 0; c < 64; ++c)
            s += part[(((size_t)b * 64 + c) * 5 + m) * 64 + d];
        v[m] = s;
        ss += s * s;
    }
    float nrm = fmaxf(sqrtf(ss), 1e-12f);
    for (int m = 0; m < 5; ++m) out[((size_t)b * 5 + m) * 64 + d] = v[m] / nrm;
    if (d < 5) {
        float mx = -1e30f;
        for (int c = 0; c < 64; ++c)
            mx = fmaxf(mx, maxpart[((size_t)b * 64 + c) * 5 + d]);
        out[OFF_SCORES + b * 5 + d] = mx;
    }
}

extern "C" void kernel_launch(void* const* d_in, const int* in_sizes, int n_in,
                              void* d_out, int out_size, void* d_ws, size_t ws_size,
                              hipStream_t stream) {
    const float* feat  = (const float*)d_in[0];   // (4,16384,64)
    const int*   edges = (const int*)d_in[1];     // (4,2,131072)
    const float* wts   = (const float*)d_in[2];   // (4,131072)
    const float* init  = (const float*)d_in[3];   // (4,16384,128)
    float* out = (float*)d_out;

    // workspace layout (bf16 h: 65536 rows x 64 uints = 16 MB each)
    unsigned* hA = (unsigned*)d_ws;
    unsigned* hB = hA + (size_t)BN * 64;
    int* row_start  = (int*)(hB + (size_t)BN * 64);   // 65537 (+pad)
    int* cursor     = row_start + 65544;              // 65536
    int* deg        = cursor + BN;                    // 65536
    int* hist       = deg + BN;                       // 256 (memset with deg)
    int* blockSums  = hist + 256;                     // 256
    int* blockSums2 = blockSums + 256;                // 256
    int* bucketCur  = blockSums2 + 256;               // 256
    int* perm       = bucketCur + 256;                // 65536
    int* prow       = perm + BN;                      // 65537 (+pad)
    int2* cw        = (int2*)(prow + 65544);          // PAD_CAP int2 (~5.8 MB)
    int2* cw2       = cw + PAD_CAP;                   // PAD_CAP int2 (~5.8 MB)
    float* part     = (float*)(cw2 + PAD_CAP);        // 4*64*5*64 = 81920
    float* maxpart  = part + 81920;                   // 1280

    // CSR build
    hipMemsetAsync(deg, 0, (BN + 256) * sizeof(int), stream);   // deg + hist
    k_count<<<TOTE / 256, 256, 0, stream>>>(edges, wts, deg);
    k_scan1<<<256, 256, 0, stream>>>(deg, blockSums);
    k_scan3<<<256, 256, 0, stream>>>(deg, blockSums, row_start, cursor);
    k_scatter<<<TOTE / 256, 256, 0, stream>>>(edges, wts, cursor, cw);
    k_sort<<<BN / 256, 256, 0, stream>>>(row_start, deg, cw);
    // degree-bucket grouping + perm-order edge layout
    k_hist<<<BN / 256, 256, 0, stream>>>(deg, hist);
    k_bucketscan<<<1, 256, 0, stream>>>(hist, bucketCur);
    k_permscatter<<<BN / 256, 256, 0, stream>>>(deg, bucketCur, perm);
    k_pscan1<<<256, 256, 0, stream>>>(deg, perm, blockSums2);
    k_pscan3<<<256, 256, 0, stream>>>(deg, perm, blockSums2, prow);
    k_copy<<<BN / 256, 256, 0, stream>>>(row_start, prow, perm, deg, cw, cw2);

    // 25 propagation iterations; iter 0 reads f32 init directly
    k_prop<true><<<BN / 16, 256, 0, stream>>>(init, hA, prow, cw2, perm);
    const unsigned* src = hA;
    for (int it = 1; it < ITERS; ++it) {
        unsigned* dst = (it & 1) ? hB : hA;
        k_prop<false><<<BN / 16, 256, 0, stream>>>(src, dst, prow, cw2, perm);
        src = dst;
    }

    // competition + outputs
    k_masks<<<BN / 4, 256, 0, stream>>>(src, out + OFF_MASKS);
    k_nfpart<<<4 * 64, 256, 0, stream>>>(feat, out + OFF_MASKS, part, maxpart);
    k_nffinal<<<4, 64, 0, stream>>>(part, maxpart, out);
}

// Round 10
// 535.863 us; speedup vs baseline: 2.9692x; 1.0417x over previous
//
#include <hip/hip_runtime.h>

// Problem constants
#define B_    4
#define N_    16384
#define D_    64
#define Q_    128
#define E_    131072
#define M_    4
#define BN    65536        // B*N
#define TOTE  524288       // B*E
#define ITERS 25
#define PAD_CAP (TOTE + 3 * BN + 64)   // padded-CSR capacity (edges)

// Output layout (f32, concatenated flat):
//   nf:         (4,5,64)      = 1280   @ 0
//   masks_ext:  (4,5,128,128) = 327680 @ 1280
//   node_scores:(4,5)         = 20     @ 328960
#define OFF_MASKS 1280
#define OFF_SCORES 328960

__constant__ int c_agidx[4] = {0, 5461, 10922, 16383};

// pack two f32 -> (bf16,bf16) in one uint, RTNE
__device__ __forceinline__ unsigned pack_bf16x2(float x, float y) {
    unsigned ux = __float_as_uint(x);
    unsigned uy = __float_as_uint(y);
    ux = (ux + 0x7fffu + ((ux >> 16) & 1u)) >> 16;          // low 16 = bf16(x)
    uy = (uy + 0x7fffu + ((uy >> 16) & 1u)) & 0xffff0000u;  // high 16 = bf16(y)
    return ux | uy;
}

// ---------- CSR build ----------
__global__ void k_count(const int* __restrict__ edges, const float* __restrict__ wts,
                        int* __restrict__ deg) {
    int idx = blockIdx.x * blockDim.x + threadIdx.x;
    if (idx >= TOTE) return;
    int b = idx >> 17;           // / E_
    int e = idx & (E_ - 1);
    float w = wts[idx];          // (B,E) flat == idx
    if (w > 0.5f) {
        int row = edges[(b * 2) * E_ + e];
        atomicAdd(&deg[row], 1);
    }
}

// ---- parallel scan over padded degrees ----
__global__ __launch_bounds__(256) void k_scan1(const int* __restrict__ deg,
                                               int* __restrict__ blockSums) {
    int i = blockIdx.x * 256 + threadIdx.x;
    int v = (deg[i] + 3) & ~3;
    #pragma unroll
    for (int off = 1; off < 64; off <<= 1) v += __shfl_xor(v, off, 64);
    __shared__ int ws[4];
    int lane = threadIdx.x & 63, w = threadIdx.x >> 6;
    if (lane == 0) ws[w] = v;
    __syncthreads();
    if (threadIdx.x == 0)
        blockSums[blockIdx.x] = ws[0] + ws[1] + ws[2] + ws[3];
}

// each block redundantly scans the 256 block sums, then rescans its 256 rows
__global__ __launch_bounds__(256) void k_scan3(const int* __restrict__ deg,
                                               const int* __restrict__ blockSums,
                                               int* __restrict__ row_start,
                                               int* __restrict__ cursor) {
    int t = threadIdx.x;
    int lane = t & 63, w = t >> 6;
    __shared__ int offs[256];
    __shared__ int wtotA[4];
    __shared__ int wtotB[4];

    int bs = blockSums[t];
    int binc = bs;
    #pragma unroll
    for (int off = 1; off < 64; off <<= 1) {
        int u = __shfl_up(binc, off, 64);
        if (lane >= off) binc += u;
    }
    if (lane == 63) wtotA[w] = binc;
    __syncthreads();
    int badd = 0;
    for (int j = 0; j < w; ++j) badd += wtotA[j];
    offs[t] = binc + badd - bs;
    if (blockIdx.x == 0 && t == 255) row_start[BN] = binc + badd;
    __syncthreads();
    int blockOff = offs[blockIdx.x];

    int i = blockIdx.x * 256 + t;
    int v = (deg[i] + 3) & ~3;
    int incl = v;
    #pragma unroll
    for (int off = 1; off < 64; off <<= 1) {
        int u = __shfl_up(incl, off, 64);
        if (lane >= off) incl += u;
    }
    if (lane == 63) wtotB[w] = incl;
    __syncthreads();
    int wadd = 0;
    for (int j = 0; j < w; ++j) wadd += wtotB[j];
    int rs = blockOff + wadd + incl - v;
    row_start[i] = rs;
    cursor[i] = rs;
}

__global__ void k_scatter(const int* __restrict__ edges, const float* __restrict__ wts,
                          int* __restrict__ cursor, int2* __restrict__ cw) {
    int idx = blockIdx.x * blockDim.x + threadIdx.x;
    if (idx >= TOTE) return;
    int b = idx >> 17;
    int e = idx & (E_ - 1);
    float w = wts[idx];
    if (w > 0.5f) {
        int row = edges[(b * 2) * E_ + e];
        int col = edges[(b * 2) * E_ + E_ + e];
        int pos = atomicAdd(&cursor[row], 1);
        cw[pos] = make_int2(col, __float_as_int(w));
    }
}

// Deterministic order within each row's REAL segment: sort by (col, w-bits).
// Also writes the (0,0) padding entries up to the 4-aligned row end.
__global__ void k_sort(const int* __restrict__ row_start, const int* __restrict__ deg,
                       int2* __restrict__ cw) {
    int n = blockIdx.x * blockDim.x + threadIdx.x;
    if (n >= BN) return;
    int s = row_start[n], epos = s + deg[n], pend = row_start[n + 1];
    for (int i = s + 1; i < epos; ++i) {
        int2 v = cw[i];
        unsigned long long key =
            ((unsigned long long)(unsigned)v.x << 32) | (unsigned)v.y;
        int j = i - 1;
        while (j >= s) {
            int2 u = cw[j];
            unsigned long long kj =
                ((unsigned long long)(unsigned)u.x << 32) | (unsigned)u.y;
            if (kj <= key) break;
            cw[j + 1] = u;
            --j;
        }
        cw[j + 1] = v;
    }
    for (int i = epos; i < pend; ++i) cw[i] = make_int2(0, 0);
}

// ---------- propagation: persistent-ish waves, 4 sequential 2-node pairs ----------
// Grid = 2048 blocks (8192 waves); wave w handles pairs (gid, gid+32768) for
// gid = w + k*8192, k=0..3. Pair body identical to the R6 kernel (bit-exact
// per-node math; shorter node's last chunk replays with w=0).
template <bool F32IN>
__global__ __launch_bounds__(256) void k_prop(const void* __restrict__ hin,
                                              unsigned* __restrict__ hout,
                                              const int* __restrict__ row_start,
                                              const int2* __restrict__ cw) {
    int lane = threadIdx.x & 63;
    int wid = (blockIdx.x << 2) + (threadIdx.x >> 6);   // 0..8191

    auto gather = [&](int col) -> float2 {
        if constexpr (F32IN) {
            return ((const float2*)hin)[((size_t)col << 6) + lane];
        } else {
            unsigned p = ((const unsigned*)hin)[((size_t)col << 6) + lane];
            float2 r;
            r.x = __uint_as_float(p << 16);
            r.y = __uint_as_float(p & 0xffff0000u);
            return r;
        }
    };

    #pragma unroll 1
    for (int k = 0; k < 4; ++k) {
        int gid = wid + (k << 13);                        // 0..32767
        int uA = __builtin_amdgcn_readfirstlane(gid);
        int uB = uA + 32768;
        int sA = row_start[uA], eA = row_start[uA + 1];
        int sB = row_start[uB], eB = row_start[uB + 1];
        int cA = (eA - sA) >> 2, cB = (eB - sB) >> 2;
        int nmax = cA > cB ? cA : cB;
        int baseA = cA ? sA : sB;
        int baseB = cB ? sB : sA;
        int lastA = (cA ? cA : 1) - 1;
        int lastB = (cB ? cB : 1) - 1;

        float axA = 0.f, ayA = 0.f, axB = 0.f, ayB = 0.f;
        for (int j = 0; j < nmax; ++j) {
            int jA = j < lastA ? j : lastA;
            int jB = j < lastB ? j : lastB;
            const int4* qA = (const int4*)(cw + baseA + (jA << 2));
            const int4* qB = (const int4*)(cw + baseB + (jB << 2));
            int4 a0 = qA[0], a1 = qA[1];
            int4 b0 = qB[0], b1 = qB[1];
            float2 vA0 = gather(a0.x);
            float2 vA1 = gather(a0.z);
            float2 vA2 = gather(a1.x);
            float2 vA3 = gather(a1.z);
            float2 vB0 = gather(b0.x);
            float2 vB1 = gather(b0.z);
            float2 vB2 = gather(b1.x);
            float2 vB3 = gather(b1.z);
            bool okA = j < cA, okB = j < cB;
            float wA0 = okA ? __int_as_float(a0.y) : 0.f;
            float wA1 = okA ? __int_as_float(a0.w) : 0.f;
            float wA2 = okA ? __int_as_float(a1.y) : 0.f;
            float wA3 = okA ? __int_as_float(a1.w) : 0.f;
            float wB0 = okB ? __int_as_float(b0.y) : 0.f;
            float wB1 = okB ? __int_as_float(b0.w) : 0.f;
            float wB2 = okB ? __int_as_float(b1.y) : 0.f;
            float wB3 = okB ? __int_as_float(b1.w) : 0.f;
            axA = fmaf(wA0, vA0.x, axA); ayA = fmaf(wA0, vA0.y, ayA);
            axA = fmaf(wA1, vA1.x, axA); ayA = fmaf(wA1, vA1.y, ayA);
            axA = fmaf(wA2, vA2.x, axA); ayA = fmaf(wA2, vA2.y, ayA);
            axA = fmaf(wA3, vA3.x, axA); ayA = fmaf(wA3, vA3.y, ayA);
            axB = fmaf(wB0, vB0.x, axB); ayB = fmaf(wB0, vB0.y, ayB);
            axB = fmaf(wB1, vB1.x, axB); ayB = fmaf(wB1, vB1.y, ayB);
            axB = fmaf(wB2, vB2.x, axB); ayB = fmaf(wB2, vB2.y, ayB);
            axB = fmaf(wB3, vB3.x, axB); ayB = fmaf(wB3, vB3.y, ayB);
        }
        float ssA = axA * axA + ayA * ayA;
        float ssB = axB * axB + ayB * ayB;
        #pragma unroll
        for (int off = 32; off; off >>= 1) {
            ssA += __shfl_xor(ssA, off, 64);
            ssB += __shfl_xor(ssB, off, 64);
        }
        float invA = 1.0f / (sqrtf(ssA) + 1e-8f);
        float invB = 1.0f / (sqrtf(ssB) + 1e-8f);
        hout[((size_t)uA << 6) + lane] = pack_bf16x2(axA * invA, ayA * invA);
        hout[((size_t)uB << 6) + lane] = pack_bf16x2(axB * invB, ayB * invB);
    }
}

// ---------- competition: wave per row (bf16 h) ----------
__global__ __launch_bounds__(256) void k_masks(const unsigned* __restrict__ h,
                                               float* __restrict__ masks) {
    int wave = threadIdx.x >> 6;
    int lane = threadIdx.x & 63;
    int n = blockIdx.x * 4 + wave;      // global row 0..65535
    int b = n >> 14;
    int nl = n & (N_ - 1);
    unsigned vp = h[((size_t)n << 6) + lane];
    float vx = __uint_as_float(vp << 16);
    float vy = __uint_as_float(vp & 0xffff0000u);
    float dot[4];
    #pragma unroll
    for (int m = 0; m < 4; ++m) {
        int an = b * N_ + c_agidx[m];
        unsigned ap = h[((size_t)an << 6) + lane];
        float axx = __uint_as_float(ap << 16);
        float ayy = __uint_as_float(ap & 0xffff0000u);
        float d = vx * axx + vy * ayy;
        #pragma unroll
        for (int off = 32; off; off >>= 1) d += __shfl_xor(d, off, 64);
        dot[m] = d;
    }
    const float scl = 0.0883883476483184405501055452631f; // 1/sqrt(128)
    float l0 = dot[0] * scl, l1 = dot[1] * scl, l2 = dot[2] * scl, l3 = dot[3] * scl;
    float mx = fmaxf(fmaxf(fmaxf(l0, l1), fmaxf(l2, l3)), 0.f);
    float e0 = expf(l0 - mx), e1 = expf(l1 - mx), e2 = expf(l2 - mx),
          e3 = expf(l3 - mx), e4 = expf(0.f - mx);
    float den = e0 + e1 + e2 + e3 + e4;
    if (lane < 5) {
        float p = (lane == 0) ? e0 : (lane == 1) ? e1 : (lane == 2) ? e2
                  : (lane == 3) ? e3 : e4;
        masks[((size_t)b * 5 + lane) * N_ + nl] = p / den;
    }
}

// ---------- nf partials + chunk maxes: ONE feat pass for all 5 masks ----------
__global__ __launch_bounds__(256) void k_nfpart(const float* __restrict__ feat,
                                                const float* __restrict__ masks,
                                                float* __restrict__ part,
                                                float* __restrict__ maxpart) {
    int b = blockIdx.x >> 6;
    int chunk = blockIdx.x & 63;
    int d = threadIdx.x & 63;
    int g = threadIdx.x >> 6;   // wave id 0..3
    int n0 = chunk * 256 + g * 64;
    const float* fb = feat + (size_t)b * N_ * D_;
    float acc[5] = {0.f, 0.f, 0.f, 0.f, 0.f};
    float mxv[5] = {-1e30f, -1e30f, -1e30f, -1e30f, -1e30f};
    for (int i = 0; i < 64; ++i) {
        int n = n0 + i;
        float fv = fb[(size_t)n * D_ + d];
        #pragma unroll
        for (int m = 0; m < 5; ++m) {
            float mv = masks[((size_t)b * 5 + m) * N_ + n];
            acc[m] = fmaf(fv, mv, acc[m]);
            mxv[m] = fmaxf(mxv[m], mv);
        }
    }
    __shared__ float lds[4][5][64];
    __shared__ float lmx[4][5];
    #pragma unroll
    for (int m = 0; m < 5; ++m) lds[g][m][d] = acc[m];
    if (d == 0) {
        #pragma unroll
        for (int m = 0; m < 5; ++m) lmx[g][m] = mxv[m];
    }
    __syncthreads();
    if (g == 0) {
        #pragma unroll
        for (int m = 0; m < 5; ++m) {
            float s = lds[0][m][d] + lds[1][m][d] + lds[2][m][d] + lds[3][m][d];
            part[(((size_t)b * 64 + chunk) * 5 + m) * 64 + d] = s;
            if (d == 0)
                maxpart[((size_t)b * 64 + chunk) * 5 + m] =
                    fmaxf(fmaxf(lmx[0][m], lmx[1][m]), fmaxf(lmx[2][m], lmx[3][m]));
        }
    }
}

// ---------- final: sum chunks, normalize over m-axis, scores ----------
__global__ void k_nffinal(const float* __restrict__ part, const float* __restrict__ maxpart,
                          float* __restrict__ out) {
    int b = blockIdx.x;     // 4 blocks
    int d = threadIdx.x;    // 64 threads
    float v[5];
    float ss = 0.f;
    for (int m = 0; m < 5; ++m) {
        float s = 0.f;
        for (int c = 0; c < 64; ++c)
            s += part[(((size_t)b * 64 + c) * 5 + m) * 64 + d];
        v[m] = s;
        ss += s * s;
    }
    float nrm = fmaxf(sqrtf(ss), 1e-12f);
    for (int m = 0; m < 5; ++m) out[((size_t)b * 5 + m) * 64 + d] = v[m] / nrm;
    if (d < 5) {
        float mx = -1e30f;
        for (int c = 0; c < 64; ++c)
            mx = fmaxf(mx, maxpart[((size_t)b * 64 + c) * 5 + d]);
        out[OFF_SCORES + b * 5 + d] = mx;
    }
}

extern "C" void kernel_launch(void* const* d_in, const int* in_sizes, int n_in,
                              void* d_out, int out_size, void* d_ws, size_t ws_size,
                              hipStream_t stream) {
    const float* feat  = (const float*)d_in[0];   // (4,16384,64)
    const int*   edges = (const int*)d_in[1];     // (4,2,131072)
    const float* wts   = (const float*)d_in[2];   // (4,131072)
    const float* init  = (const float*)d_in[3];   // (4,16384,128)
    float* out = (float*)d_out;

    // workspace layout (bf16 h: 65536 rows x 64 uints = 16 MB each)
    unsigned* hA = (unsigned*)d_ws;
    unsigned* hB = hA + (size_t)BN * 64;
    int* row_start  = (int*)(hB + (size_t)BN * 64);   // 65537 (+pad)
    int* cursor     = row_start + 65544;              // 65536
    int* deg        = cursor + BN;                    // 65536
    int* blockSums  = deg + BN;                       // 256
    int2* cw        = (int2*)(blockSums + 256);       // PAD_CAP int2 (~5.8 MB)
    float* part     = (float*)(cw + PAD_CAP);         // 4*64*5*64 = 81920
    float* maxpart  = part + 81920;                   // 1280

    // CSR build (padded rows, interleaved (col,w) pairs; padding written by k_sort)
    hipMemsetAsync(deg, 0, BN * sizeof(int), stream);
    k_count<<<TOTE / 256, 256, 0, stream>>>(edges, wts, deg);
    k_scan1<<<256, 256, 0, stream>>>(deg, blockSums);
    k_scan3<<<256, 256, 0, stream>>>(deg, blockSums, row_start, cursor);
    k_scatter<<<TOTE / 256, 256, 0, stream>>>(edges, wts, cursor, cw);
    k_sort<<<BN / 256, 256, 0, stream>>>(row_start, deg, cw);

    // 25 propagation iterations; iter 0 reads f32 init directly
    k_prop<true><<<2048, 256, 0, stream>>>(init, hA, row_start, cw);
    const unsigned* src = hA;
    for (int it = 1; it < ITERS; ++it) {
        unsigned* dst = (it & 1) ? hB : hA;
        k_prop<false><<<2048, 256, 0, stream>>>(src, dst, row_start, cw);
        src = dst;
    }

    // competition + outputs
    k_masks<<<BN / 4, 256, 0, stream>>>(src, out + OFF_MASKS);
    k_nfpart<<<4 * 64, 256, 0, stream>>>(feat, out + OFF_MASKS, part, maxpart);
    k_nffinal<<<4, 64, 0, stream>>>(part, maxpart, out);
}

// Round 11
// 535.749 us; speedup vs baseline: 2.9698x; 1.0002x over previous
//
#include <hip/hip_runtime.h>

// Problem constants
#define B_    4
#define N_    16384
#define D_    64
#define Q_    128
#define E_    131072
#define M_    4
#define BN    65536        // B*N
#define TOTE  524288       // B*E
#define ITERS 25
#define PAD_CAP (TOTE + 3 * BN + 64)   // padded-CSR capacity (edges)

// Output layout (f32, concatenated flat):
//   nf:         (4,5,64)      = 1280   @ 0
//   masks_ext:  (4,5,128,128) = 327680 @ 1280
//   node_scores:(4,5)         = 20     @ 328960
#define OFF_MASKS 1280
#define OFF_SCORES 328960

__constant__ int c_agidx[4] = {0, 5461, 10922, 16383};

// pack two f32 -> (bf16,bf16) in one uint, RTNE
__device__ __forceinline__ unsigned pack_bf16x2(float x, float y) {
    unsigned ux = __float_as_uint(x);
    unsigned uy = __float_as_uint(y);
    ux = (ux + 0x7fffu + ((ux >> 16) & 1u)) >> 16;          // low 16 = bf16(x)
    uy = (uy + 0x7fffu + ((uy >> 16) & 1u)) & 0xffff0000u;  // high 16 = bf16(y)
    return ux | uy;
}

// ---------- CSR build ----------
__global__ void k_count(const int* __restrict__ edges, const float* __restrict__ wts,
                        int* __restrict__ deg) {
    int idx = blockIdx.x * blockDim.x + threadIdx.x;
    if (idx >= TOTE) return;
    int b = idx >> 17;           // / E_
    int e = idx & (E_ - 1);
    float w = wts[idx];          // (B,E) flat == idx
    if (w > 0.5f) {
        int row = edges[(b * 2) * E_ + e];
        atomicAdd(&deg[row], 1);
    }
}

// ---- parallel scan over padded degrees (original node order) ----
__global__ __launch_bounds__(256) void k_scan1(const int* __restrict__ deg,
                                               int* __restrict__ blockSums) {
    int i = blockIdx.x * 256 + threadIdx.x;
    int v = (deg[i] + 3) & ~3;
    #pragma unroll
    for (int off = 1; off < 64; off <<= 1) v += __shfl_xor(v, off, 64);
    __shared__ int ws[4];
    int lane = threadIdx.x & 63, w = threadIdx.x >> 6;
    if (lane == 0) ws[w] = v;
    __syncthreads();
    if (threadIdx.x == 0)
        blockSums[blockIdx.x] = ws[0] + ws[1] + ws[2] + ws[3];
}

__global__ __launch_bounds__(256) void k_scan3(const int* __restrict__ deg,
                                               const int* __restrict__ blockSums,
                                               int* __restrict__ row_start,
                                               int* __restrict__ cursor) {
    int t = threadIdx.x;
    int lane = t & 63, w = t >> 6;
    __shared__ int offs[256];
    __shared__ int wtotA[4];
    __shared__ int wtotB[4];

    int bs = blockSums[t];
    int binc = bs;
    #pragma unroll
    for (int off = 1; off < 64; off <<= 1) {
        int u = __shfl_up(binc, off, 64);
        if (lane >= off) binc += u;
    }
    if (lane == 63) wtotA[w] = binc;
    __syncthreads();
    int badd = 0;
    for (int j = 0; j < w; ++j) badd += wtotA[j];
    offs[t] = binc + badd - bs;
    if (blockIdx.x == 0 && t == 255) row_start[BN] = binc + badd;
    __syncthreads();
    int blockOff = offs[blockIdx.x];

    int i = blockIdx.x * 256 + t;
    int v = (deg[i] + 3) & ~3;
    int incl = v;
    #pragma unroll
    for (int off = 1; off < 64; off <<= 1) {
        int u = __shfl_up(incl, off, 64);
        if (lane >= off) incl += u;
    }
    if (lane == 63) wtotB[w] = incl;
    __syncthreads();
    int wadd = 0;
    for (int j = 0; j < w; ++j) wadd += wtotB[j];
    int rs = blockOff + wadd + incl - v;
    row_start[i] = rs;
    cursor[i] = rs;
}

__global__ void k_scatter(const int* __restrict__ edges, const float* __restrict__ wts,
                          int* __restrict__ cursor, int2* __restrict__ cw) {
    int idx = blockIdx.x * blockDim.x + threadIdx.x;
    if (idx >= TOTE) return;
    int b = idx >> 17;
    int e = idx & (E_ - 1);
    float w = wts[idx];
    if (w > 0.5f) {
        int row = edges[(b * 2) * E_ + e];
        int col = edges[(b * 2) * E_ + E_ + e];
        int pos = atomicAdd(&cursor[row], 1);
        cw[pos] = make_int2(col, __float_as_int(w));
    }
}

// Deterministic order within each row's REAL segment: sort by (col, w-bits)
// in ORIGINAL col ids (fixes each row's accumulation sequence for all later
// layouts). Padding (0,0) written to the 4-aligned row end.
__global__ void k_sort(const int* __restrict__ row_start, const int* __restrict__ deg,
                       int2* __restrict__ cw) {
    int n = blockIdx.x * blockDim.x + threadIdx.x;
    if (n >= BN) return;
    int s = row_start[n], epos = s + deg[n], pend = row_start[n + 1];
    for (int i = s + 1; i < epos; ++i) {
        int2 v = cw[i];
        unsigned long long key =
            ((unsigned long long)(unsigned)v.x << 32) | (unsigned)v.y;
        int j = i - 1;
        while (j >= s) {
            int2 u = cw[j];
            unsigned long long kj =
                ((unsigned long long)(unsigned)u.x << 32) | (unsigned)u.y;
            if (kj <= key) break;
            cw[j + 1] = u;
            --j;
        }
        cw[j + 1] = v;
    }
    for (int i = epos; i < pend; ++i) cw[i] = make_int2(0, 0);
}

// ---- degree-bucket counting sort via per-block LDS histograms ----
// perm order is atomic-nondeterministic; output bits don't depend on it
// (per-row accumulation sequence fixed by k_sort; padding carries w=0).
__global__ __launch_bounds__(256) void k_hist(const int* __restrict__ deg,
                                              int* __restrict__ hist) {
    __shared__ int lh[256];
    int t = threadIdx.x;
    lh[t] = 0;
    __syncthreads();
    int n = blockIdx.x * 256 + t;
    int c = (deg[n] + 3) >> 2;
    if (c > 255) c = 255;
    atomicAdd(&lh[c], 1);
    __syncthreads();
    int cnt = lh[t];
    if (cnt) atomicAdd(&hist[t], cnt);
}

__global__ __launch_bounds__(256) void k_bucketscan(const int* __restrict__ hist,
                                                    int* __restrict__ bucketCur) {
    int t = threadIdx.x;
    int lane = t & 63, w = t >> 6;
    int v = hist[t];
    int incl = v;
    #pragma unroll
    for (int off = 1; off < 64; off <<= 1) {
        int u = __shfl_up(incl, off, 64);
        if (lane >= off) incl += u;
    }
    __shared__ int wtot[4];
    if (lane == 63) wtot[w] = incl;
    __syncthreads();
    int wadd = 0;
    for (int j = 0; j < w; ++j) wadd += wtot[j];
    bucketCur[t] = incl + wadd - v;
}

__global__ __launch_bounds__(256) void k_permscatter(const int* __restrict__ deg,
                                                     int* __restrict__ bucketCur,
                                                     int* __restrict__ perm) {
    __shared__ int lh[256];
    __shared__ int lbase[256];
    int t = threadIdx.x;
    lh[t] = 0;
    __syncthreads();
    int n = blockIdx.x * 256 + t;
    int c = (deg[n] + 3) >> 2;
    if (c > 255) c = 255;
    int lpos = atomicAdd(&lh[c], 1);
    __syncthreads();
    int cnt = lh[t];
    lbase[t] = cnt ? atomicAdd(&bucketCur[t], cnt) : 0;
    __syncthreads();
    perm[lbase[c] + lpos] = n;
}

__global__ void k_inv(const int* __restrict__ perm, int* __restrict__ inv) {
    int i = blockIdx.x * 256 + threadIdx.x;
    inv[perm[i]] = i;
}

// ---- scan of padded degrees in PERM order -> prow ----
__global__ __launch_bounds__(256) void k_pscan1(const int* __restrict__ deg,
                                                const int* __restrict__ perm,
                                                int* __restrict__ blockSums2) {
    int i = blockIdx.x * 256 + threadIdx.x;
    int v = (deg[perm[i]] + 3) & ~3;
    #pragma unroll
    for (int off = 1; off < 64; off <<= 1) v += __shfl_xor(v, off, 64);
    __shared__ int ws[4];
    int lane = threadIdx.x & 63, w = threadIdx.x >> 6;
    if (lane == 0) ws[w] = v;
    __syncthreads();
    if (threadIdx.x == 0)
        blockSums2[blockIdx.x] = ws[0] + ws[1] + ws[2] + ws[3];
}

__global__ __launch_bounds__(256) void k_pscan3(const int* __restrict__ deg,
                                                const int* __restrict__ perm,
                                                const int* __restrict__ blockSums2,
                                                int* __restrict__ prow) {
    int t = threadIdx.x;
    int lane = t & 63, w = t >> 6;
    __shared__ int offs[256];
    __shared__ int wtotA[4];
    __shared__ int wtotB[4];

    int bs = blockSums2[t];
    int binc = bs;
    #pragma unroll
    for (int off = 1; off < 64; off <<= 1) {
        int u = __shfl_up(binc, off, 64);
        if (lane >= off) binc += u;
    }
    if (lane == 63) wtotA[w] = binc;
    __syncthreads();
    int badd = 0;
    for (int j = 0; j < w; ++j) badd += wtotA[j];
    offs[t] = binc + badd - bs;
    if (blockIdx.x == 0 && t == 255) prow[BN] = binc + badd;
    __syncthreads();
    int blockOff = offs[blockIdx.x];

    int i = blockIdx.x * 256 + t;
    int v = (deg[perm[i]] + 3) & ~3;
    int incl = v;
    #pragma unroll
    for (int off = 1; off < 64; off <<= 1) {
        int u = __shfl_up(incl, off, 64);
        if (lane >= off) incl += u;
    }
    if (lane == 63) wtotB[w] = incl;
    __syncthreads();
    int wadd = 0;
    for (int j = 0; j < w; ++j) wadd += wtotB[j];
    prow[i] = blockOff + wadd + incl - v;
}

// ---- copy segments into perm-order layout; cw2 = relabeled cols, cw2o = orig ----
__global__ __launch_bounds__(256) void k_copy(const int* __restrict__ row_start,
                                              const int* __restrict__ prow,
                                              const int* __restrict__ perm,
                                              const int* __restrict__ deg,
                                              const int* __restrict__ inv,
                                              const int2* __restrict__ cw,
                                              int2* __restrict__ cw2,
                                              int2* __restrict__ cw2o) {
    int i = blockIdx.x * 256 + threadIdx.x;
    int n = perm[i];
    int src = row_start[n];
    int dst = prow[i];
    int nq = (deg[n] + 3) >> 2;
    for (int j = 0; j < nq; ++j) {
        const int4* s = (const int4*)(cw + src + (j << 2));
        int4 x0 = s[0], x1 = s[1];
        int4 r0 = x0, r1 = x1;
        r0.x = inv[x0.x]; r0.z = inv[x0.z];
        r1.x = inv[x1.x]; r1.z = inv[x1.z];
        ((int4*)(cw2 + dst + (j << 2)))[0] = r0;
        ((int4*)(cw2 + dst + (j << 2)))[1] = r1;
        ((int4*)(cw2o + dst + (j << 2)))[0] = x0;
        ((int4*)(cw2o + dst + (j << 2)))[1] = x1;
    }
}

// ---------- propagation: adjacent relabeled rows (2w, 2w+1) per wave ----------
// Bucket-sorted layout: adjacent rows have matched chunk counts -> replay ~0;
// cw2 reads contiguous per wave; hout writes = 512 B streaming per wave.
// F32IN: gathers from init (ORIGINAL layout) via cw2o's original cols.
// Per-row math bit-exact (same sorted edge sequence; padding w=0).
template <bool F32IN>
__global__ __launch_bounds__(256) void k_prop(const void* __restrict__ hin,
                                              unsigned* __restrict__ hout,
                                              const int* __restrict__ prow,
                                              const int2* __restrict__ cwp) {
    int lane = threadIdx.x & 63;
    int w = (blockIdx.x << 2) + (threadIdx.x >> 6);     // 0..32767
    int base = __builtin_amdgcn_readfirstlane(w << 1);  // new row ids base, base+1
    int sA = prow[base], sB = prow[base + 1], eB = prow[base + 2];
    int cA = (sB - sA) >> 2, cB = (eB - sB) >> 2;
    int nmax = cA > cB ? cA : cB;
    int baseA = cA ? sA : sB;
    int baseB = cB ? sB : sA;
    int lastA = (cA ? cA : 1) - 1;
    int lastB = (cB ? cB : 1) - 1;

    auto gather = [&](int col) -> float2 {
        if constexpr (F32IN) {
            return ((const float2*)hin)[((size_t)col << 6) + lane];
        } else {
            unsigned p = ((const unsigned*)hin)[((size_t)col << 6) + lane];
            float2 r;
            r.x = __uint_as_float(p << 16);
            r.y = __uint_as_float(p & 0xffff0000u);
            return r;
        }
    };

    float axA = 0.f, ayA = 0.f, axB = 0.f, ayB = 0.f;
    for (int j = 0; j < nmax; ++j) {
        int jA = j < lastA ? j : lastA;
        int jB = j < lastB ? j : lastB;
        const int4* qA = (const int4*)(cwp + baseA + (jA << 2));
        const int4* qB = (const int4*)(cwp + baseB + (jB << 2));
        int4 a0 = qA[0], a1 = qA[1];
        int4 b0 = qB[0], b1 = qB[1];
        float2 vA0 = gather(a0.x);
        float2 vA1 = gather(a0.z);
        float2 vA2 = gather(a1.x);
        float2 vA3 = gather(a1.z);
        float2 vB0 = gather(b0.x);
        float2 vB1 = gather(b0.z);
        float2 vB2 = gather(b1.x);
        float2 vB3 = gather(b1.z);
        bool okA = j < cA, okB = j < cB;
        float wA0 = okA ? __int_as_float(a0.y) : 0.f;
        float wA1 = okA ? __int_as_float(a0.w) : 0.f;
        float wA2 = okA ? __int_as_float(a1.y) : 0.f;
        float wA3 = okA ? __int_as_float(a1.w) : 0.f;
        float wB0 = okB ? __int_as_float(b0.y) : 0.f;
        float wB1 = okB ? __int_as_float(b0.w) : 0.f;
        float wB2 = okB ? __int_as_float(b1.y) : 0.f;
        float wB3 = okB ? __int_as_float(b1.w) : 0.f;
        axA = fmaf(wA0, vA0.x, axA); ayA = fmaf(wA0, vA0.y, ayA);
        axA = fmaf(wA1, vA1.x, axA); ayA = fmaf(wA1, vA1.y, ayA);
        axA = fmaf(wA2, vA2.x, axA); ayA = fmaf(wA2, vA2.y, ayA);
        axA = fmaf(wA3, vA3.x, axA); ayA = fmaf(wA3, vA3.y, ayA);
        axB = fmaf(wB0, vB0.x, axB); ayB = fmaf(wB0, vB0.y, ayB);
        axB = fmaf(wB1, vB1.x, axB); ayB = fmaf(wB1, vB1.y, ayB);
        axB = fmaf(wB2, vB2.x, axB); ayB = fmaf(wB2, vB2.y, ayB);
        axB = fmaf(wB3, vB3.x, axB); ayB = fmaf(wB3, vB3.y, ayB);
    }
    float ssA = axA * axA + ayA * ayA;
    float ssB = axB * axB + ayB * ayB;
    #pragma unroll
    for (int off = 32; off; off >>= 1) {
        ssA += __shfl_xor(ssA, off, 64);
        ssB += __shfl_xor(ssB, off, 64);
    }
    float invA = 1.0f / (sqrtf(ssA) + 1e-8f);
    float invB = 1.0f / (sqrtf(ssB) + 1e-8f);
    hout[((size_t)base << 6) + lane] = pack_bf16x2(axA * invA, ayA * invA);
    hout[((size_t)(base + 1) << 6) + lane] = pack_bf16x2(axB * invB, ayB * invB);
}

// ---------- competition: wave per (original) row; h is in relabeled layout ----------
__global__ __launch_bounds__(256) void k_masks(const unsigned* __restrict__ h,
                                               const int* __restrict__ inv,
                                               float* __restrict__ masks) {
    int wave = threadIdx.x >> 6;
    int lane = threadIdx.x & 63;
    int n = blockIdx.x * 4 + wave;      // original row 0..65535
    int un = __builtin_amdgcn_readfirstlane(n);
    int b = un >> 14;
    int nl = un & (N_ - 1);
    int rn = inv[un];                    // relabeled position (s_load)
    unsigned vp = h[((size_t)rn << 6) + lane];
    float vx = __uint_as_float(vp << 16);
    float vy = __uint_as_float(vp & 0xffff0000u);
    float dot[4];
    #pragma unroll
    for (int m = 0; m < 4; ++m) {
        int an = inv[b * N_ + c_agidx[m]];
        unsigned ap = h[((size_t)an << 6) + lane];
        float axx = __uint_as_float(ap << 16);
        float ayy = __uint_as_float(ap & 0xffff0000u);
        float d = vx * axx + vy * ayy;
        #pragma unroll
        for (int off = 32; off; off >>= 1) d += __shfl_xor(d, off, 64);
        dot[m] = d;
    }
    const float scl = 0.0883883476483184405501055452631f; // 1/sqrt(128)
    float l0 = dot[0] * scl, l1 = dot[1] * scl, l2 = dot[2] * scl, l3 = dot[3] * scl;
    float mx = fmaxf(fmaxf(fmaxf(l0, l1), fmaxf(l2, l3)), 0.f);
    float e0 = expf(l0 - mx), e1 = expf(l1 - mx), e2 = expf(l2 - mx),
          e3 = expf(l3 - mx), e4 = expf(0.f - mx);
    float den = e0 + e1 + e2 + e3 + e4;
    if (lane < 5) {
        float p = (lane == 0) ? e0 : (lane == 1) ? e1 : (lane == 2) ? e2
                  : (lane == 3) ? e3 : e4;
        masks[((size_t)b * 5 + lane) * N_ + nl] = p / den;
    }
}

// ---------- nf partials + chunk maxes: ONE feat pass for all 5 masks ----------
__global__ __launch_bounds__(256) void k_nfpart(const float* __restrict__ feat,
                                                const float* __restrict__ masks,
                                                float* __restrict__ part,
                                                float* __restrict__ maxpart) {
    int b = blockIdx.x >> 6;
    int chunk = blockIdx.x & 63;
    int d = threadIdx.x & 63;
    int g = threadIdx.x >> 6;   // wave id 0..3
    int n0 = chunk * 256 + g * 64;
    const float* fb = feat + (size_t)b * N_ * D_;
    float acc[5] = {0.f, 0.f, 0.f, 0.f, 0.f};
    float mxv[5] = {-1e30f, -1e30f, -1e30f, -1e30f, -1e30f};
    for (int i = 0; i < 64; ++i) {
        int n = n0 + i;
        float fv = fb[(size_t)n * D_ + d];
        #pragma unroll
        for (int m = 0; m < 5; ++m) {
            float mv = masks[((size_t)b * 5 + m) * N_ + n];
            acc[m] = fmaf(fv, mv, acc[m]);
            mxv[m] = fmaxf(mxv[m], mv);
        }
    }
    __shared__ float lds[4][5][64];
    __shared__ float lmx[4][5];
    #pragma unroll
    for (int m = 0; m < 5; ++m) lds[g][m][d] = acc[m];
    if (d == 0) {
        #pragma unroll
        for (int m = 0; m < 5; ++m) lmx[g][m] = mxv[m];
    }
    __syncthreads();
    if (g == 0) {
        #pragma unroll
        for (int m = 0; m < 5; ++m) {
            float s = lds[0][m][d] + lds[1][m][d] + lds[2][m][d] + lds[3][m][d];
            part[(((size_t)b * 64 + chunk) * 5 + m) * 64 + d] = s;
            if (d == 0)
                maxpart[((size_t)b * 64 + chunk) * 5 + m] =
                    fmaxf(fmaxf(lmx[0][m], lmx[1][m]), fmaxf(lmx[2][m], lmx[3][m]));
        }
    }
}

// ---------- final: sum chunks, normalize over m-axis, scores ----------
__global__ void k_nffinal(const float* __restrict__ part, const float* __restrict__ maxpart,
                          float* __restrict__ out) {
    int b = blockIdx.x;     // 4 blocks
    int d = threadIdx.x;    // 64 threads
    float v[5];
    float ss = 0.f;
    for (int m = 0; m < 5; ++m) {
        float s = 0.f;
        for (int c = 0; c < 64; ++c)
            s += part[(((size_t)b * 64 + c) * 5 + m) * 64 + d];
        v[m] = s;
        ss += s * s;
    }
    float nrm = fmaxf(sqrtf(ss), 1e-12f);
    for (int m = 0; m < 5; ++m) out[((size_t)b * 5 + m) * 64 + d] = v[m] / nrm;
    if (d < 5) {
        float mx = -1e30f;
        for (int c = 0; c < 64; ++c)
            mx = fmaxf(mx, maxpart[((size_t)b * 64 + c) * 5 + d]);
        out[OFF_SCORES + b * 5 + d] = mx;
    }
}

extern "C" void kernel_launch(void* const* d_in, const int* in_sizes, int n_in,
                              void* d_out, int out_size, void* d_ws, size_t ws_size,
                              hipStream_t stream) {
    const float* feat  = (const float*)d_in[0];   // (4,16384,64)
    const int*   edges = (const int*)d_in[1];     // (4,2,131072)
    const float* wts   = (const float*)d_in[2];   // (4,131072)
    const float* init  = (const float*)d_in[3];   // (4,16384,128)
    float* out = (float*)d_out;

    // workspace layout (bf16 h: 65536 rows x 64 uints = 16 MB each)
    unsigned* hA = (unsigned*)d_ws;
    unsigned* hB = hA + (size_t)BN * 64;
    int* row_start  = (int*)(hB + (size_t)BN * 64);   // 65537 (+pad)
    int* cursor     = row_start + 65544;              // 65536
    int* deg        = cursor + BN;                    // 65536
    int* hist       = deg + BN;                       // 256 (memset with deg)
    int* blockSums  = hist + 256;                     // 256
    int* blockSums2 = blockSums + 256;                // 256
    int* bucketCur  = blockSums2 + 256;               // 256
    int* perm       = bucketCur + 256;                // 65536
    int* inv        = perm + BN;                      // 65536
    int* prow       = inv + BN;                       // 65537 (+pad)
    int2* cw        = (int2*)(prow + 65544);          // PAD_CAP int2 (~5.8 MB)
    int2* cw2       = cw + PAD_CAP;                   // ~5.8 MB
    int2* cw2o      = cw2 + PAD_CAP;                  // ~5.8 MB
    float* part     = (float*)(cw2o + PAD_CAP);       // 4*64*5*64 = 81920
    float* maxpart  = part + 81920;                   // 1280

    // CSR build
    hipMemsetAsync(deg, 0, (BN + 256) * sizeof(int), stream);   // deg + hist
    k_count<<<TOTE / 256, 256, 0, stream>>>(edges, wts, deg);
    k_scan1<<<256, 256, 0, stream>>>(deg, blockSums);
    k_scan3<<<256, 256, 0, stream>>>(deg, blockSums, row_start, cursor);
    k_scatter<<<TOTE / 256, 256, 0, stream>>>(edges, wts, cursor, cw);
    k_sort<<<BN / 256, 256, 0, stream>>>(row_start, deg, cw);
    // bucket-sorted relabeling + perm-order edge layout (orig + relabeled cols)
    k_hist<<<BN / 256, 256, 0, stream>>>(deg, hist);
    k_bucketscan<<<1, 256, 0, stream>>>(hist, bucketCur);
    k_permscatter<<<BN / 256, 256, 0, stream>>>(deg, bucketCur, perm);
    k_inv<<<BN / 256, 256, 0, stream>>>(perm, inv);
    k_pscan1<<<256, 256, 0, stream>>>(deg, perm, blockSums2);
    k_pscan3<<<256, 256, 0, stream>>>(deg, perm, blockSums2, prow);
    k_copy<<<BN / 256, 256, 0, stream>>>(row_start, prow, perm, deg, inv, cw, cw2, cw2o);

    // 25 propagation iterations; iter 0 gathers f32 init (orig layout) via cw2o
    k_prop<true><<<BN / 8, 256, 0, stream>>>(init, hA, prow, cw2o);
    const unsigned* src = hA;
    for (int it = 1; it < ITERS; ++it) {
        unsigned* dst = (it & 1) ? hB : hA;
        k_prop<false><<<BN / 8, 256, 0, stream>>>(src, dst, prow, cw2);
        src = dst;
    }

    // competition + outputs
    k_masks<<<BN / 4, 256, 0, stream>>>(src, inv, out + OFF_MASKS);
    k_nfpart<<<4 * 64, 256, 0, stream>>>(feat, out + OFF_MASKS, part, maxpart);
    k_nffinal<<<4, 64, 0, stream>>>(part, maxpart, out);
}